// Round 14
// baseline (1169.860 us; speedup 1.0000x reference)
//
#include <hip/hip_runtime.h>
#include <hip/hip_bf16.h>

#define EPS 1e-5f
typedef unsigned short bfr;   // raw bf16 bits
typedef unsigned short hfr;   // raw f16 bits
typedef _Float16 h2v __attribute__((ext_vector_type(2)));
typedef _Float16 f16x8 __attribute__((ext_vector_type(8)));
typedef float f32x4 __attribute__((ext_vector_type(4)));

#if defined(__has_builtin)
#if __has_builtin(__builtin_amdgcn_fdot2)
#define HAS_FDOT2 1
#endif
#endif

static inline int cdiv(int a, int b){ return (a + b - 1) / b; }

__device__ __forceinline__ float bf2f(bfr u){ return __uint_as_float((unsigned)u << 16); }
__device__ __forceinline__ bfr f2bf(float f){
  unsigned u = __float_as_uint(f);
  u += 0x7fffu + ((u >> 16) & 1u);
  return (bfr)(u >> 16);
}
__device__ __forceinline__ unsigned pack2bf(float a, float b){
  return (unsigned)f2bf(a) | ((unsigned)f2bf(b) << 16);
}
__device__ __forceinline__ float h2f(hfr u){ _Float16 h; __builtin_memcpy(&h, &u, 2); return (float)h; }
__device__ __forceinline__ _Float16 asH(hfr u){ _Float16 h; __builtin_memcpy(&h, &u, 2); return h; }
__device__ __forceinline__ hfr f2h(float f){ _Float16 h = (_Float16)f; hfr u; __builtin_memcpy(&u, &h, 2); return u; }
__device__ __forceinline__ unsigned pack2h(float a, float b){
  return (unsigned)f2h(a) | ((unsigned)f2h(b) << 16);
}
__device__ __forceinline__ h2v u2h2(unsigned u){ h2v r; __builtin_memcpy(&r, &u, 4); return r; }
__device__ __forceinline__ unsigned h22u(h2v h){ unsigned u; __builtin_memcpy(&u, &h, 4); return u; }
__device__ __forceinline__ float dot2(h2v a, h2v b, float c){
#ifdef HAS_FDOT2
  return __builtin_amdgcn_fdot2(a, b, c, false);
#else
  return c + (float)a.x * (float)b.x + (float)a.y * (float)b.y;
#endif
}

// ---------------- dtype detection (bf16 vs f32 inputs) ----------------
__global__ __launch_bounds__(256) void detect_kernel(const bfr* __restrict__ xr, int nwords, int* __restrict__ flag){
  int i = threadIdx.x;
  int bad = 0;
  if (i < nwords){
    bfr lo = xr[2 * i];
    int e = (lo >> 7) & 0xFF;
    bool plausible = ((lo & 0x7FFF) == 0) || (e >= 97 && e <= 157);
    bad = plausible ? 0 : 1;
  }
  __shared__ int s[256];
  s[threadIdx.x] = bad; __syncthreads();
  for (int st = 128; st; st >>= 1){
    if (threadIdx.x < st) s[threadIdx.x] += s[threadIdx.x + st];
    __syncthreads();
  }
  if (threadIdx.x == 0) *flag = (s[0] > 32) ? 1 : 0;
}

// ---------------- batched adaptive convert ----------------
#define NPAR 31
struct ParamPtrs { const void* p[NPAR]; };
struct ParamOfs  { int off[NPAR + 1]; };

__global__ __launch_bounds__(256) void acvt_batch_kernel(ParamPtrs pp, ParamOfs po,
                                                         float* __restrict__ out, int total,
                                                         const int* __restrict__ flag){
  int g = blockIdx.x * 256 + threadIdx.x;
  if (g >= total) return;
  int isf = *flag;
  int t = 0;
  while (po.off[t + 1] <= g) ++t;
  int i = g - po.off[t];
  out[g] = isf ? ((const float*)pp.p[t])[i] : bf2f(((const bfr*)pp.p[t])[i]);
}

// ---------------- counting sort of edges by dst (multi-block scan) ----------------
__global__ __launch_bounds__(256) void deg_kernel(const int* __restrict__ dst, int* __restrict__ deg, int E){
  int e = blockIdx.x * 256 + threadIdx.x;
  if (e < E) atomicAdd(&deg[dst[e]], 1);
}

__global__ __launch_bounds__(256) void scan1_kernel(const int* __restrict__ deg, int* __restrict__ locoff,
                                                    int* __restrict__ bsum, int N){
  __shared__ int s[256];
  int i = blockIdx.x * 256 + threadIdx.x;
  int v = (i < N) ? deg[i] : 0;
  s[threadIdx.x] = v; __syncthreads();
  for (int st = 1; st < 256; st <<= 1){
    int u = (threadIdx.x >= st) ? s[threadIdx.x - st] : 0;
    __syncthreads();
    s[threadIdx.x] += u;
    __syncthreads();
  }
  if (i < N) locoff[i] = s[threadIdx.x] - v;
  if (threadIdx.x == 255) bsum[blockIdx.x] = s[255];
}

__global__ __launch_bounds__(256) void scan2_kernel(int* __restrict__ bsum, int nb){
  __shared__ int s[256];
  const int t = threadIdx.x;
  int carry = 0;
  for (int base = 0; base < nb; base += 256){
    int v = (base + t < nb) ? bsum[base + t] : 0;
    s[t] = v; __syncthreads();
    for (int st = 1; st < 256; st <<= 1){
      int u = (t >= st) ? s[t - st] : 0;
      __syncthreads();
      s[t] += u;
      __syncthreads();
    }
    if (base + t < nb) bsum[base + t] = carry + s[t] - v;
    carry += s[255];
    __syncthreads();
  }
}

__global__ __launch_bounds__(256) void scan3_kernel(const int* __restrict__ locoff, const int* __restrict__ bsum,
                                                    int* __restrict__ row_off, int* __restrict__ cur,
                                                    int N, int E){
  int i = blockIdx.x * 256 + threadIdx.x;
  if (i < N){
    int v = locoff[i] + bsum[blockIdx.x];
    row_off[i] = v; cur[i] = v;
  }
  if (i == 0) row_off[N] = E;
}

__global__ __launch_bounds__(256) void scatter_kernel(const int* __restrict__ src, const int* __restrict__ dst,
                                                      int* __restrict__ cur, int* __restrict__ ssrc,
                                                      int* __restrict__ sdst, int E){
  int e = blockIdx.x * 256 + threadIdx.x;
  if (e < E){
    int d = dst[e];
    int p = atomicAdd(&cur[d], 1);
    ssrc[p] = src[e];
    sdst[p] = d;
  }
}

// ---------------- fused P/Q GEMM: y=0 -> P = A@(Wtop-Wbot)+ba ; y=1 -> Q = A@Wbot ----------------
template<bool FIRST>
__global__ __launch_bounds__(256) void gemmPQ_kernel(const void* __restrict__ Av, int lda,
                                                     const float* __restrict__ Wa, int d,
                                                     const float* __restrict__ ba,
                                                     hfr* __restrict__ P, hfr* __restrict__ Q, int N){
  __shared__ unsigned WsU[64 * 64];
  const int y = blockIdx.y;
  const int tot = d * 64;
  if (FIRST){
    float* Ws = (float*)WsU;
    for (int i = threadIdx.x; i < tot; i += 256)
      Ws[i] = y ? Wa[tot + i] : (Wa[i] - Wa[tot + i]);
  } else {
    for (int i = threadIdx.x; i < 32 * 64; i += 256){
      int p = i >> 6, c = i & 63;
      int i0 = (2 * p) * 64 + c, i1 = (2 * p + 1) * 64 + c;
      float w0 = y ? Wa[tot + i0] : (Wa[i0] - Wa[tot + i0]);
      float w1 = y ? Wa[tot + i1] : (Wa[i1] - Wa[tot + i1]);
      WsU[i] = pack2h(w0, w1);
    }
  }
  __syncthreads();
  const int row = blockIdx.x * 256 + threadIdx.x;
  if (row >= N) return;
  float acc[64];
#pragma unroll
  for (int c = 0; c < 64; ++c) acc[c] = 0.f;
  if (FIRST){
    const float* Ws = (const float*)WsU;
    const float* Af = (const float*)Av + (size_t)row * lda;
    for (int k = 0; k < d; ++k){
      float a = Af[k];
      const float* wr = Ws + k * 64;
#pragma unroll
      for (int c4 = 0; c4 < 16; ++c4){
        float4 w = *(const float4*)(wr + 4 * c4);
        acc[4*c4+0] += a * w.x; acc[4*c4+1] += a * w.y;
        acc[4*c4+2] += a * w.z; acc[4*c4+3] += a * w.w;
      }
    }
  } else {
    const hfr* Ah = (const hfr*)Av + (size_t)row * lda;
#pragma unroll
    for (int k8 = 0; k8 < 8; ++k8){
      uint4 av = *(const uint4*)(Ah + k8 * 8);
      unsigned pr[4] = {av.x, av.y, av.z, av.w};
#pragma unroll
      for (int pi = 0; pi < 4; ++pi){
        h2v ap = u2h2(pr[pi]);
        const unsigned* wr = WsU + (k8 * 4 + pi) * 64;
#pragma unroll
        for (int c = 0; c < 64; ++c) acc[c] = dot2(ap, u2h2(wr[c]), acc[c]);
      }
    }
  }
  if (!y){
#pragma unroll
    for (int c = 0; c < 64; ++c) acc[c] += ba[c];
  }
  unsigned p[32];
#pragma unroll
  for (int c = 0; c < 64; c += 2) p[c / 2] = pack2h(acc[c], acc[c + 1]);
  hfr* outp = (y ? Q : P) + (size_t)row * 64;
  uint4* op = (uint4*)outp;
#pragma unroll
  for (int i = 0; i < 8; ++i) op[i] = make_uint4(p[4*i], p[4*i+1], p[4*i+2], p[4*i+3]);
}

// ---------------- generic row-per-thread GEMM (MLP; A f16, K mult of 64), optional inlined BN fold ----------------
template<int NOUT, bool FOLD>
__global__ __launch_bounds__(256) void gemm_kernel(const hfr* __restrict__ Ah, int lda,
                                                   const float* __restrict__ W, int ldw,
                                                   const float* __restrict__ bias,
                                                   const float* __restrict__ stats, float cntInv,
                                                   const float* __restrict__ g, const float* __restrict__ be,
                                                   hfr* __restrict__ Ov, int ldo,
                                                   int nrows, int K, int relu){
  __shared__ unsigned Wp[32 * NOUT];
  __shared__ float aS[256], bbS[256], bfull[NOUT], bsum[256];
  const int ct = blockIdx.y * NOUT;
  const int tid = threadIdx.x;
  if (FOLD){
    for (int k = tid; k < K; k += 256){
      float mu = stats[k] * cntInv;
      float var = stats[K + k] * cntInv - mu * mu;
      float ai = g[k] * rsqrtf(var + EPS);
      aS[k] = ai; bbS[k] = be[k] - ai * mu;
    }
    __syncthreads();
    constexpr int parts = 256 / NOUT;
    int c = tid % NOUT, p = tid / NOUT;
    float s = 0.f;
    for (int k = p; k < K; k += parts) s += bbS[k] * W[(size_t)k * ldw + ct + c];
    bsum[p * NOUT + c] = s;
    __syncthreads();
    if (tid < NOUT){
      float t = bias[ct + tid];
#pragma unroll
      for (int pp = 0; pp < parts; ++pp) t += bsum[pp * NOUT + tid];
      bfull[tid] = t;
    }
  }
  const int row = blockIdx.x * 256 + tid;
  float acc[NOUT];
#pragma unroll
  for (int c = 0; c < NOUT; ++c) acc[c] = 0.f;
  for (int k0 = 0; k0 < K; k0 += 64){
    __syncthreads();
    for (int i = tid; i < 32 * NOUT; i += 256){
      int p = i / NOUT, c = i - p * NOUT;
      float w0 = W[(size_t)(k0 + 2 * p) * ldw + ct + c];
      float w1 = W[(size_t)(k0 + 2 * p + 1) * ldw + ct + c];
      if (FOLD){ w0 *= aS[k0 + 2 * p]; w1 *= aS[k0 + 2 * p + 1]; }
      Wp[i] = pack2h(w0, w1);
    }
    __syncthreads();
    if (row < nrows){
      const hfr* Ap = Ah + (size_t)row * lda + k0;
#pragma unroll
      for (int k8 = 0; k8 < 8; ++k8){
        uint4 av = *(const uint4*)(Ap + k8 * 8);
        unsigned pr[4] = {av.x, av.y, av.z, av.w};
#pragma unroll
        for (int pi = 0; pi < 4; ++pi){
          h2v ap = u2h2(pr[pi]);
          const unsigned* wr = Wp + (k8 * 4 + pi) * NOUT;
#pragma unroll
          for (int c = 0; c < NOUT; ++c) acc[c] = dot2(ap, u2h2(wr[c]), acc[c]);
        }
      }
    }
  }
  __syncthreads();
  if (row >= nrows) return;
#pragma unroll
  for (int c = 0; c < NOUT; ++c){
    float b = FOLD ? bfull[c] : bias[ct + c];
    float v = acc[c] + b;
    acc[c] = relu ? fmaxf(v, 0.f) : v;
  }
  unsigned p[NOUT / 2];
#pragma unroll
  for (int c = 0; c < NOUT; c += 2) p[c / 2] = pack2h(acc[c], acc[c + 1]);
  uint4* op = (uint4*)(Ov + (size_t)row * ldo + ct);
#pragma unroll
  for (int i = 0; i < NOUT / 8; ++i) op[i] = make_uint4(p[4*i], p[4*i+1], p[4*i+2], p[4*i+3]);
}

// ---------------- passA (FLAT dst-sorted edges, 32-edge batches): BN1 stats, block-reduced atomics ----------------
__global__ __launch_bounds__(256) void passA_kernel(const hfr* __restrict__ P, const hfr* __restrict__ Q,
                                                    const int* __restrict__ ssrc, const int* __restrict__ sdst,
                                                    float* __restrict__ stats, int E){
  const int lane = threadIdx.x & 63;
  const int wid = (blockIdx.x * 256 + threadIdx.x) >> 6;
  const int nw = (gridDim.x * 256) >> 6;
  const _Float16 z16 = (_Float16)0;
  const int lim = E - 1;
  float sum = 0.f, sq = 0.f;
  for (int base = wid * 32; base < E; base += nw * 32){
    int idx = min(base + (lane & 31), lim);
    int sv = ssrc[idx];
    int dv = sdst[idx];
#pragma unroll
    for (int j = 0; j < 32; ++j){
      int sj = __shfl(sv, j, 64);
      int dj = __shfl(dv, j, 64);
      _Float16 a = asH(P[(size_t)dj * 64 + lane]) + asH(Q[(size_t)sj * 64 + lane]);
      float v = (a < z16) ? 0.f : (float)a;
      bool valid = (base + j) < E;
      sum += valid ? v : 0.f;
      sq  += valid ? v * v : 0.f;
    }
  }
  // block-level reduction: 1 wave of same-line atomics per BLOCK
  __shared__ float ls[256], lq[256];
  ls[threadIdx.x] = sum; lq[threadIdx.x] = sq;
  __syncthreads();
  if (threadIdx.x < 64){
    int c = threadIdx.x;
    atomicAdd(&stats[c], ls[c] + ls[64 + c] + ls[128 + c] + ls[192 + c]);
  } else if (threadIdx.x < 128){
    int c = threadIdx.x - 64;
    atomicAdd(&stats[64 + c], lq[c] + lq[64 + c] + lq[128 + c] + lq[192 + c]);
  }
}

// ---------------- passBC: inlined BN1 fold + MFMA 16-edge batches + BN2 stats (block-reduced) + register segment-max ----------------
// A[m=lane&15][k=quad*8+j] (verified m120); C[col=lane&15][row=quad*4+reg] (verified m89).
__global__ __launch_bounds__(256) void passBC_kernel(const hfr* __restrict__ P, const hfr* __restrict__ Q,
                                                     const int* __restrict__ ssrc, const int* __restrict__ row_off,
                                                     const float* __restrict__ statsIn, float Einv,
                                                     const float* __restrict__ g1, const float* __restrict__ be1,
                                                     const float* __restrict__ Wb, const float* __restrict__ bn,
                                                     float* __restrict__ agg, float* __restrict__ statsOut, int N){
  __shared__ _Float16 W2T[64 * 72];     // [c][k] = (f16)(a1[k]*Wb[k][c]), padded
  __shared__ _Float16 ht[4][16][72];    // per-wave 16-edge h1 tile, padded
  __shared__ float aS[64], bbS[64], b2S[64], bsum[256], qsum[256];
  const int tid = threadIdx.x;
  const int lane = tid & 63;
  const int half = lane >> 5;
  const int cl = lane & 31;
  const int wib = tid >> 6;
  const _Float16 z16 = (_Float16)0;
  if (tid < 64){
    float mu = statsIn[tid] * Einv;
    float var = statsIn[64 + tid] * Einv - mu * mu;
    float ai = g1[tid] * rsqrtf(var + EPS);
    aS[tid] = ai; bbS[tid] = be1[tid] - ai * mu;
  }
  __syncthreads();
  for (int i = tid; i < 4096; i += 256){
    int c = i >> 6, k = i & 63;
    W2T[c * 72 + k] = (_Float16)(aS[k] * Wb[(size_t)k * 64 + c]);
  }
  {
    int c = tid & 63, p = tid >> 6;   // parts = 4
    float s = 0.f;
    for (int k = p; k < 64; k += 4) s += bbS[k] * Wb[(size_t)k * 64 + c];
    bsum[p * 64 + c] = s;
  }
  __syncthreads();
  if (tid < 64) b2S[tid] = bn[tid] + bsum[tid] + bsum[64 + tid] + bsum[128 + tid] + bsum[192 + tid];
  __syncthreads();
  f16x8 Bf[4][2];
#pragma unroll
  for (int t = 0; t < 4; ++t)
#pragma unroll
    for (int h = 0; h < 2; ++h){
      int c = t * 16 + (lane & 15);
      Bf[t][h] = *(const f16x8*)&W2T[c * 72 + h * 32 + (lane >> 4) * 8];
    }
  float bc[4];
#pragma unroll
  for (int t = 0; t < 4; ++t) bc[t] = b2S[t * 16 + (lane & 15)];
  _Float16 (*hl)[72] = ht[wib];
  const int wid = (blockIdx.x * 256 + tid) >> 6;
  const int nw = (gridDim.x * 256) >> 6;
  float sumT[4] = {0.f,0.f,0.f,0.f}, sqT[4] = {0.f,0.f,0.f,0.f};
  for (int n = wid; n < N; n += nw){
    const int e0 = row_off[n], e1 = row_off[n + 1];
    if (e0 >= e1) continue;
    unsigned pw = *(const unsigned*)(P + (size_t)n * 64 + 2 * cl);
    h2v pv2 = u2h2(pw);
    const int lim = e1 - 1;
    float mxT[4] = {0.f,0.f,0.f,0.f};
    for (int eb = e0; eb < e1; eb += 16){
      int sv = ssrc[min(eb + (lane & 15), lim)];
#pragma unroll
      for (int t = 0; t < 8; ++t){           // half-wave: 2 rows/step, 16 gathers in flight
        int j = 2 * t + half;
        int sj = __shfl(sv, j, 64);
        unsigned qw = *(const unsigned*)(Q + (size_t)sj * 64 + 2 * cl);
        h2v s = pv2 + u2h2(qw);
        s.x = (s.x < z16) ? z16 : s.x;
        s.y = (s.y < z16) ? z16 : s.y;
        *(unsigned*)&hl[j][2 * cl] = h22u(s);
      }
      // intra-wave LDS RAW: compiler emits lgkmcnt wait, no barrier needed
      f16x8 A0 = *(const f16x8*)&hl[lane & 15][(lane >> 4) * 8];
      f16x8 A1 = *(const f16x8*)&hl[lane & 15][32 + (lane >> 4) * 8];
#pragma unroll
      for (int t = 0; t < 4; ++t){
        f32x4 Cv = {bc[t], bc[t], bc[t], bc[t]};
        Cv = __builtin_amdgcn_mfma_f32_16x16x32_f16(A0, Bf[t][0], Cv, 0, 0, 0);
        Cv = __builtin_amdgcn_mfma_f32_16x16x32_f16(A1, Bf[t][1], Cv, 0, 0, 0);
#pragma unroll
        for (int r = 0; r < 4; ++r){
          float v = fmaxf(Cv[r], 0.f);
          int rowi = (lane >> 4) * 4 + r;
          bool valid = (eb + rowi) < e1;
          mxT[t] = fmaxf(mxT[t], v);          // clamped dup rows mirror a real edge: max-safe
          sumT[t] += valid ? v : 0.f;
          sqT[t]  += valid ? v * v : 0.f;
        }
      }
    }
#pragma unroll
    for (int t = 0; t < 4; ++t){
      float m = mxT[t];
      m = fmaxf(m, __shfl_xor(m, 16, 64));
      m = fmaxf(m, __shfl_xor(m, 32, 64));
      mxT[t] = m;
    }
    float outv = (lane < 16) ? mxT[0] : (lane < 32) ? mxT[1] : (lane < 48) ? mxT[2] : mxT[3];
    agg[(size_t)n * 64 + lane] = outv;
  }
#pragma unroll
  for (int t = 0; t < 4; ++t){
    float s = sumT[t], q = sqT[t];
    s += __shfl_xor(s, 16, 64); s += __shfl_xor(s, 32, 64);
    q += __shfl_xor(q, 16, 64); q += __shfl_xor(q, 32, 64);
    sumT[t] = s; sqT[t] = q;
  }
  float ssel = (lane < 16) ? sumT[0] : (lane < 32) ? sumT[1] : (lane < 48) ? sumT[2] : sumT[3];
  float qsel = (lane < 16) ? sqT[0]  : (lane < 32) ? sqT[1]  : (lane < 48) ? sqT[2]  : sqT[3];
  // block-level reduction: 1 wave of same-line atomics per BLOCK
  bsum[tid] = ssel; qsum[tid] = qsel;
  __syncthreads();
  if (tid < 64){
    atomicAdd(&statsOut[tid], bsum[tid] + bsum[64 + tid] + bsum[128 + tid] + bsum[192 + tid]);
  } else if (tid < 128){
    int c = tid - 64;
    atomicAdd(&statsOut[64 + c], qsum[c] + qsum[64 + c] + qsum[128 + c] + qsum[192 + c]);
  }
}

// ---------------- fixup with inlined BN2 coefficients ----------------
__global__ __launch_bounds__(256) void fixup_kernel(const float* __restrict__ agg, const int* __restrict__ deg,
                                                    const float* __restrict__ stats, float cntInv,
                                                    const float* __restrict__ g, const float* __restrict__ be,
                                                    hfr* __restrict__ xout, int ldx, int N){
  int t = blockIdx.x * 256 + threadIdx.x;
  if (t >= N * 64) return;
  int n = t >> 6, c = t & 63;
  float mu = stats[c] * cntInv;
  float var = stats[64 + c] * cntInv - mu * mu;
  float a = g[c] * rsqrtf(var + EPS);
  float b = be[c] - a * mu;
  float v = 0.f;
  if (deg[n] > 0) v = a * agg[t] + b;
  xout[(size_t)n * ldx + c] = f2h(v);
}

// ---------------- node BN stats over f16 activations ----------------
template<int C>
__global__ __launch_bounds__(256) void statsN_kernel(const hfr* __restrict__ u, float* __restrict__ stats, int N){
  constexpr int RP = 256 / C;
  const int c = threadIdx.x % C, j = threadIdx.x / C;
  float sum = 0.f, sq = 0.f;
  for (int r = blockIdx.x * RP + j; r < N; r += gridDim.x * RP){
    float v = h2f(u[(size_t)r * C + c]);
    sum += v; sq += v * v;
  }
  __shared__ float ls[256], lq[256];
  ls[threadIdx.x] = sum; lq[threadIdx.x] = sq;
  __syncthreads();
  if (threadIdx.x < C){
    float s = 0.f, q = 0.f;
#pragma unroll
    for (int jj = 0; jj < RP; ++jj){ s += ls[jj * C + c]; q += lq[jj * C + c]; }
    atomicAdd(&stats[c], s); atomicAdd(&stats[C + c], q);
  }
}

// ---------------- head: inlined BN fold + logits + log_softmax ----------------
__global__ __launch_bounds__(256) void head_kernel(const hfr* __restrict__ u2,
                                                   const float* __restrict__ stats, float cntInv,
                                                   const float* __restrict__ g, const float* __restrict__ be,
                                                   const float* __restrict__ Wo, const float* __restrict__ bo,
                                                   void* __restrict__ out, int N, const int* __restrict__ flag){
  __shared__ float Ws[32 * 24];
  __shared__ float bs[24];
  __shared__ float aS[32], bbS[32];
  const int tid = threadIdx.x;
  if (tid < 32){
    float mu = stats[tid] * cntInv;
    float var = stats[32 + tid] * cntInv - mu * mu;
    float ai = g[tid] * rsqrtf(var + EPS);
    aS[tid] = ai; bbS[tid] = be[tid] - ai * mu;
  }
  __syncthreads();
  for (int i = tid; i < 32 * 24; i += 256){
    int k = i / 24, c = i - 24 * k;
    Ws[i] = aS[k] * Wo[(size_t)k * 24 + c];
  }
  if (tid < 24){
    float t = bo[tid];
    for (int k = 0; k < 32; ++k) t += bbS[k] * Wo[(size_t)k * 24 + tid];
    bs[tid] = t;
  }
  __syncthreads();
  int r = blockIdx.x * 256 + tid;
  if (r >= N) return;
  int isf = *flag;
  float l[24];
#pragma unroll
  for (int c = 0; c < 24; ++c) l[c] = bs[c];
  const hfr* up = u2 + (size_t)r * 32;
#pragma unroll
  for (int k = 0; k < 32; ++k){
    float v = h2f(up[k]);
#pragma unroll
    for (int c = 0; c < 24; ++c) l[c] += v * Ws[k * 24 + c];
  }
  float m = l[0];
#pragma unroll
  for (int c = 1; c < 24; ++c) m = fmaxf(m, l[c]);
  float s = 0.f;
#pragma unroll
  for (int c = 0; c < 24; ++c) s += expf(l[c] - m);
  float lse = m + logf(s);
  if (isf){
    float4* op = (float4*)((float*)out + (size_t)r * 24);
#pragma unroll
    for (int i = 0; i < 6; ++i)
      op[i] = make_float4(l[4*i] - lse, l[4*i+1] - lse, l[4*i+2] - lse, l[4*i+3] - lse);
  } else {
    unsigned p[12];
#pragma unroll
    for (int c = 0; c < 24; c += 2) p[c / 2] = pack2bf(l[c] - lse, l[c + 1] - lse);
    uint4* op = (uint4*)((bfr*)out + (size_t)r * 24);
#pragma unroll
    for (int i = 0; i < 3; ++i) op[i] = make_uint4(p[4*i], p[4*i+1], p[4*i+2], p[4*i+3]);
  }
}

// ---------------- host ----------------
// Footprint ~55 MB (ws-safe since round 3). Aliases disjoint in time:
// u_l over P+Q+agg (dead after conv loop); u1/u2 over xcat (dead after lin1).
// BN folds inlined; stat atomics block-reduced; multi-block scan;
// round-14: GWA/GWB=2048 (8 blocks/CU) + passA 32-edge batches for latency hiding.
extern "C" void kernel_launch(void* const* d_in, const int* in_sizes, int n_in,
                              void* d_out, int out_size, void* d_ws, size_t ws_size,
                              hipStream_t stream){
  const int N = in_sizes[0] / 6;
  const int E = in_sizes[31] / 2;
  const int* edge = (const int*)d_in[31];
  const int* src = edge;
  const int* dst = edge + E;

  size_t off = 0; char* basep = (char*)d_ws;
  auto alloc = [&](size_t bytes) -> void* {
    void* p = basep + off;
    off = (off + bytes + 255) & ~(size_t)255;
    return p;
  };
  // stats: 3 conv regions (256 ea: BN1[0:128) BN2[128:256)) + stN1(512) + stN2(128) + stN3(64)
  float* stA  = (float*)alloc(1472 * 4);
  float* stN1 = stA + 768;
  float* stN2 = stA + 1280;
  float* stN3 = stA + 1408;
  int*   flag = (int*)  alloc(4);
  int*   deg  = (int*)  alloc((size_t)N * 4);
  int*   rowo = (int*)  alloc((size_t)(N + 1) * 4);
  int*   cur  = (int*)  alloc((size_t)N * 4);
  int*   loco = (int*)  alloc((size_t)N * 4);
  int*   bsc  = (int*)  alloc(1024 * 4);
  int*   ssrc = (int*)  alloc((size_t)E * 4);
  int*   sdst = (int*)  alloc((size_t)E * 4);

  ParamPtrs pp; ParamOfs po;
  int hoff[32]; int total = 0;
  for (int s = 0; s < NPAR; ++s){
    int idx = (s < 30) ? (s + 1) : 0;
    pp.p[s] = d_in[idx];
    po.off[s] = total;
    hoff[idx] = total;
    total += in_sizes[idx];
  }
  po.off[NPAR] = total;
  float* pf = (float*)alloc((size_t)total * 4);

  hfr*   P    = (hfr*)  alloc((size_t)N * 64 * 2);
  hfr*   Qb   = (hfr*)  alloc((size_t)N * 64 * 2);
  float* agg  = (float*)alloc((size_t)N * 64 * 4);
  hfr*   xcat = (hfr*)  alloc((size_t)N * 192 * 2);
  hfr* u_l = (hfr*)P;                 // [N,256] f16 over P+Q+agg
  hfr* u1  = xcat;                    // [N,64]  f16
  hfr* u2  = xcat + (size_t)N * 64;   // [N,32]  f16
  (void)ws_size; (void)n_in; (void)out_size;

  dim3 B(256);
  detect_kernel<<<1, B, 0, stream>>>((const bfr*)d_in[0], 256, flag);
  acvt_batch_kernel<<<cdiv(total, 256), B, 0, stream>>>(pp, po, pf, total, flag);

  hipMemsetAsync(stA, 0, 1472 * 4, stream);
  hipMemsetAsync(deg, 0, (size_t)N * 4, stream);
  deg_kernel<<<cdiv(E, 256), B, 0, stream>>>(dst, deg, E);
  const int NBn = cdiv(N, 256);
  scan1_kernel<<<NBn, B, 0, stream>>>(deg, loco, bsc, N);
  scan2_kernel<<<1, B, 0, stream>>>(bsc, NBn);
  scan3_kernel<<<NBn, B, 0, stream>>>(loco, bsc, rowo, cur, N, E);
  scatter_kernel<<<cdiv(E, 256), B, 0, stream>>>(src, dst, cur, ssrc, sdst, E);

  const int NB = cdiv(N, 256);
  const int GWA = 2048, GWB = 2048;
  const float Einv = 1.f / (float)E;
  for (int k = 0; k < 3; ++k){
    const float *Wa_k, *ba_k, *ga_k, *bea_k, *Wb_k, *bb_k, *gb_k, *beb_k;
    if (k == 0){
      Wa_k = pf + hoff[1]; ba_k = pf + hoff[2]; ga_k = pf + hoff[3]; bea_k = pf + hoff[4];
      Wb_k = pf + hoff[5]; bb_k = pf + hoff[6]; gb_k = pf + hoff[7]; beb_k = pf + hoff[8];
    } else {
      int kk = k - 1;
      Wa_k = pf + hoff[9]  + (size_t)kk * 128 * 64;
      ba_k = pf + hoff[10] + kk * 64;
      ga_k = pf + hoff[11] + kk * 64;
      bea_k= pf + hoff[12] + kk * 64;
      Wb_k = pf + hoff[13] + (size_t)kk * 64 * 64;
      bb_k = pf + hoff[14] + kk * 64;
      gb_k = pf + hoff[15] + kk * 64;
      beb_k= pf + hoff[16] + kk * 64;
    }
    float* st1 = stA + k * 256;
    float* st2 = st1 + 128;
    if (k == 0)
      gemmPQ_kernel<true><<<dim3(NB, 2), B, 0, stream>>>(pf + hoff[0], 6, Wa_k, 6, ba_k, P, Qb, N);
    else
      gemmPQ_kernel<false><<<dim3(NB, 2), B, 0, stream>>>(xcat + (size_t)(k - 1) * 64, 192, Wa_k, 64, ba_k, P, Qb, N);
    passA_kernel<<<GWA, B, 0, stream>>>(P, Qb, ssrc, sdst, st1, E);
    passBC_kernel<<<GWB, B, 0, stream>>>(P, Qb, ssrc, rowo, st1, Einv, ga_k, bea_k, Wb_k, bb_k,
                                         agg, st2, N);
    fixup_kernel<<<cdiv(N * 64, 256), B, 0, stream>>>(agg, deg, st2, Einv, gb_k, beb_k,
                                                      xcat + (size_t)k * 64, 192, N);
  }

  // node MLP (folds inlined into consuming GEMMs / head)
  gemm_kernel<64, false><<<dim3(NB, 4), B, 0, stream>>>(xcat, 192, pf + hoff[17], 256, pf + hoff[18],
                                                        nullptr, 0.f, nullptr, nullptr,
                                                        u_l, 256, N, 192, 1);
  statsN_kernel<256><<<512, B, 0, stream>>>(u_l, stN1, N);
  gemm_kernel<64, true><<<dim3(NB, 1), B, 0, stream>>>(u_l, 256, pf + hoff[21], 64, pf + hoff[22],
                                                       stN1, 1.f / (float)N, pf + hoff[19], pf + hoff[20],
                                                       u1, 64, N, 256, 1);
  statsN_kernel<64><<<512, B, 0, stream>>>(u1, stN2, N);
  gemm_kernel<32, true><<<dim3(NB, 1), B, 0, stream>>>(u1, 64, pf + hoff[25], 32, pf + hoff[26],
                                                       stN2, 1.f / (float)N, pf + hoff[23], pf + hoff[24],
                                                       u2, 32, N, 64, 1);
  statsN_kernel<32><<<512, B, 0, stream>>>(u2, stN3, N);
  head_kernel<<<cdiv(N, 256), B, 0, stream>>>(u2, stN3, 1.f / (float)N, pf + hoff[27], pf + hoff[28],
                                              pf + hoff[29], pf + hoff[30], d_out, N, flag);
}

// Round 15
// 1039.828 us; speedup vs baseline: 1.1251x; 1.1251x over previous
//
#include <hip/hip_runtime.h>
#include <hip/hip_bf16.h>

#define EPS 1e-5f
typedef unsigned short bfr;   // raw bf16 bits
typedef unsigned short hfr;   // raw f16 bits
typedef _Float16 h2v __attribute__((ext_vector_type(2)));
typedef _Float16 f16x8 __attribute__((ext_vector_type(8)));
typedef float f32x4 __attribute__((ext_vector_type(4)));

#if defined(__has_builtin)
#if __has_builtin(__builtin_amdgcn_fdot2)
#define HAS_FDOT2 1
#endif
#endif

static inline int cdiv(int a, int b){ return (a + b - 1) / b; }

__device__ __forceinline__ float bf2f(bfr u){ return __uint_as_float((unsigned)u << 16); }
__device__ __forceinline__ bfr f2bf(float f){
  unsigned u = __float_as_uint(f);
  u += 0x7fffu + ((u >> 16) & 1u);
  return (bfr)(u >> 16);
}
__device__ __forceinline__ unsigned pack2bf(float a, float b){
  return (unsigned)f2bf(a) | ((unsigned)f2bf(b) << 16);
}
__device__ __forceinline__ float h2f(hfr u){ _Float16 h; __builtin_memcpy(&h, &u, 2); return (float)h; }
__device__ __forceinline__ _Float16 asH(hfr u){ _Float16 h; __builtin_memcpy(&h, &u, 2); return h; }
__device__ __forceinline__ hfr f2h(float f){ _Float16 h = (_Float16)f; hfr u; __builtin_memcpy(&u, &h, 2); return u; }
__device__ __forceinline__ unsigned pack2h(float a, float b){
  return (unsigned)f2h(a) | ((unsigned)f2h(b) << 16);
}
__device__ __forceinline__ h2v u2h2(unsigned u){ h2v r; __builtin_memcpy(&r, &u, 4); return r; }
__device__ __forceinline__ unsigned h22u(h2v h){ unsigned u; __builtin_memcpy(&u, &h, 4); return u; }
__device__ __forceinline__ float dot2(h2v a, h2v b, float c){
#ifdef HAS_FDOT2
  return __builtin_amdgcn_fdot2(a, b, c, false);
#else
  return c + (float)a.x * (float)b.x + (float)a.y * (float)b.y;
#endif
}

// ---------------- dtype detection (bf16 vs f32 inputs) ----------------
__global__ __launch_bounds__(256) void detect_kernel(const bfr* __restrict__ xr, int nwords, int* __restrict__ flag){
  int i = threadIdx.x;
  int bad = 0;
  if (i < nwords){
    bfr lo = xr[2 * i];
    int e = (lo >> 7) & 0xFF;
    bool plausible = ((lo & 0x7FFF) == 0) || (e >= 97 && e <= 157);
    bad = plausible ? 0 : 1;
  }
  __shared__ int s[256];
  s[threadIdx.x] = bad; __syncthreads();
  for (int st = 128; st; st >>= 1){
    if (threadIdx.x < st) s[threadIdx.x] += s[threadIdx.x + st];
    __syncthreads();
  }
  if (threadIdx.x == 0) *flag = (s[0] > 32) ? 1 : 0;
}

// ---------------- batched adaptive convert ----------------
#define NPAR 31
struct ParamPtrs { const void* p[NPAR]; };
struct ParamOfs  { int off[NPAR + 1]; };

__global__ __launch_bounds__(256) void acvt_batch_kernel(ParamPtrs pp, ParamOfs po,
                                                         float* __restrict__ out, int total,
                                                         const int* __restrict__ flag){
  int g = blockIdx.x * 256 + threadIdx.x;
  if (g >= total) return;
  int isf = *flag;
  int t = 0;
  while (po.off[t + 1] <= g) ++t;
  int i = g - po.off[t];
  out[g] = isf ? ((const float*)pp.p[t])[i] : bf2f(((const bfr*)pp.p[t])[i]);
}

// ---------------- counting sort of edges by dst (multi-block scan) ----------------
__global__ __launch_bounds__(256) void deg_kernel(const int* __restrict__ dst, int* __restrict__ deg, int E){
  int e = blockIdx.x * 256 + threadIdx.x;
  if (e < E) atomicAdd(&deg[dst[e]], 1);
}

__global__ __launch_bounds__(256) void scan1_kernel(const int* __restrict__ deg, int* __restrict__ locoff,
                                                    int* __restrict__ bsum, int N){
  __shared__ int s[256];
  int i = blockIdx.x * 256 + threadIdx.x;
  int v = (i < N) ? deg[i] : 0;
  s[threadIdx.x] = v; __syncthreads();
  for (int st = 1; st < 256; st <<= 1){
    int u = (threadIdx.x >= st) ? s[threadIdx.x - st] : 0;
    __syncthreads();
    s[threadIdx.x] += u;
    __syncthreads();
  }
  if (i < N) locoff[i] = s[threadIdx.x] - v;
  if (threadIdx.x == 255) bsum[blockIdx.x] = s[255];
}

__global__ __launch_bounds__(256) void scan2_kernel(int* __restrict__ bsum, int nb){
  __shared__ int s[256];
  const int t = threadIdx.x;
  int carry = 0;
  for (int base = 0; base < nb; base += 256){
    int v = (base + t < nb) ? bsum[base + t] : 0;
    s[t] = v; __syncthreads();
    for (int st = 1; st < 256; st <<= 1){
      int u = (t >= st) ? s[t - st] : 0;
      __syncthreads();
      s[t] += u;
      __syncthreads();
    }
    if (base + t < nb) bsum[base + t] = carry + s[t] - v;
    carry += s[255];
    __syncthreads();
  }
}

__global__ __launch_bounds__(256) void scan3_kernel(const int* __restrict__ locoff, const int* __restrict__ bsum,
                                                    int* __restrict__ row_off, int* __restrict__ cur,
                                                    int N, int E){
  int i = blockIdx.x * 256 + threadIdx.x;
  if (i < N){
    int v = locoff[i] + bsum[blockIdx.x];
    row_off[i] = v; cur[i] = v;
  }
  if (i == 0) row_off[N] = E;
}

__global__ __launch_bounds__(256) void scatter_kernel(const int* __restrict__ src, const int* __restrict__ dst,
                                                      int* __restrict__ cur, int* __restrict__ ssrc,
                                                      int* __restrict__ sdst, int E){
  int e = blockIdx.x * 256 + threadIdx.x;
  if (e < E){
    int d = dst[e];
    int p = atomicAdd(&cur[d], 1);
    ssrc[p] = src[e];
    sdst[p] = d;
  }
}

// ---------------- fused P/Q GEMM: y=0 -> P = A@(Wtop-Wbot)+ba ; y=1 -> Q = A@Wbot ----------------
template<bool FIRST>
__global__ __launch_bounds__(256) void gemmPQ_kernel(const void* __restrict__ Av, int lda,
                                                     const float* __restrict__ Wa, int d,
                                                     const float* __restrict__ ba,
                                                     hfr* __restrict__ P, hfr* __restrict__ Q, int N){
  __shared__ unsigned WsU[64 * 64];
  const int y = blockIdx.y;
  const int tot = d * 64;
  if (FIRST){
    float* Ws = (float*)WsU;
    for (int i = threadIdx.x; i < tot; i += 256)
      Ws[i] = y ? Wa[tot + i] : (Wa[i] - Wa[tot + i]);
  } else {
    for (int i = threadIdx.x; i < 32 * 64; i += 256){
      int p = i >> 6, c = i & 63;
      int i0 = (2 * p) * 64 + c, i1 = (2 * p + 1) * 64 + c;
      float w0 = y ? Wa[tot + i0] : (Wa[i0] - Wa[tot + i0]);
      float w1 = y ? Wa[tot + i1] : (Wa[i1] - Wa[tot + i1]);
      WsU[i] = pack2h(w0, w1);
    }
  }
  __syncthreads();
  const int row = blockIdx.x * 256 + threadIdx.x;
  if (row >= N) return;
  float acc[64];
#pragma unroll
  for (int c = 0; c < 64; ++c) acc[c] = 0.f;
  if (FIRST){
    const float* Ws = (const float*)WsU;
    const float* Af = (const float*)Av + (size_t)row * lda;
    for (int k = 0; k < d; ++k){
      float a = Af[k];
      const float* wr = Ws + k * 64;
#pragma unroll
      for (int c4 = 0; c4 < 16; ++c4){
        float4 w = *(const float4*)(wr + 4 * c4);
        acc[4*c4+0] += a * w.x; acc[4*c4+1] += a * w.y;
        acc[4*c4+2] += a * w.z; acc[4*c4+3] += a * w.w;
      }
    }
  } else {
    const hfr* Ah = (const hfr*)Av + (size_t)row * lda;
#pragma unroll
    for (int k8 = 0; k8 < 8; ++k8){
      uint4 av = *(const uint4*)(Ah + k8 * 8);
      unsigned pr[4] = {av.x, av.y, av.z, av.w};
#pragma unroll
      for (int pi = 0; pi < 4; ++pi){
        h2v ap = u2h2(pr[pi]);
        const unsigned* wr = WsU + (k8 * 4 + pi) * 64;
#pragma unroll
        for (int c = 0; c < 64; ++c) acc[c] = dot2(ap, u2h2(wr[c]), acc[c]);
      }
    }
  }
  if (!y){
#pragma unroll
    for (int c = 0; c < 64; ++c) acc[c] += ba[c];
  }
  unsigned p[32];
#pragma unroll
  for (int c = 0; c < 64; c += 2) p[c / 2] = pack2h(acc[c], acc[c + 1]);
  hfr* outp = (y ? Q : P) + (size_t)row * 64;
  uint4* op = (uint4*)outp;
#pragma unroll
  for (int i = 0; i < 8; ++i) op[i] = make_uint4(p[4*i], p[4*i+1], p[4*i+2], p[4*i+3]);
}

// ---------------- generic row-per-thread GEMM (MLP; A f16, K mult of 64), optional inlined BN fold ----------------
template<int NOUT, bool FOLD>
__global__ __launch_bounds__(256) void gemm_kernel(const hfr* __restrict__ Ah, int lda,
                                                   const float* __restrict__ W, int ldw,
                                                   const float* __restrict__ bias,
                                                   const float* __restrict__ stats, float cntInv,
                                                   const float* __restrict__ g, const float* __restrict__ be,
                                                   hfr* __restrict__ Ov, int ldo,
                                                   int nrows, int K, int relu){
  __shared__ unsigned Wp[32 * NOUT];
  __shared__ float aS[256], bbS[256], bfull[NOUT], bsum[256];
  const int ct = blockIdx.y * NOUT;
  const int tid = threadIdx.x;
  if (FOLD){
    for (int k = tid; k < K; k += 256){
      float mu = stats[k] * cntInv;
      float var = stats[K + k] * cntInv - mu * mu;
      float ai = g[k] * rsqrtf(var + EPS);
      aS[k] = ai; bbS[k] = be[k] - ai * mu;
    }
    __syncthreads();
    constexpr int parts = 256 / NOUT;
    int c = tid % NOUT, p = tid / NOUT;
    float s = 0.f;
    for (int k = p; k < K; k += parts) s += bbS[k] * W[(size_t)k * ldw + ct + c];
    bsum[p * NOUT + c] = s;
    __syncthreads();
    if (tid < NOUT){
      float t = bias[ct + tid];
#pragma unroll
      for (int pp = 0; pp < parts; ++pp) t += bsum[pp * NOUT + tid];
      bfull[tid] = t;
    }
  }
  const int row = blockIdx.x * 256 + tid;
  float acc[NOUT];
#pragma unroll
  for (int c = 0; c < NOUT; ++c) acc[c] = 0.f;
  for (int k0 = 0; k0 < K; k0 += 64){
    __syncthreads();
    for (int i = tid; i < 32 * NOUT; i += 256){
      int p = i / NOUT, c = i - p * NOUT;
      float w0 = W[(size_t)(k0 + 2 * p) * ldw + ct + c];
      float w1 = W[(size_t)(k0 + 2 * p + 1) * ldw + ct + c];
      if (FOLD){ w0 *= aS[k0 + 2 * p]; w1 *= aS[k0 + 2 * p + 1]; }
      Wp[i] = pack2h(w0, w1);
    }
    __syncthreads();
    if (row < nrows){
      const hfr* Ap = Ah + (size_t)row * lda + k0;
#pragma unroll
      for (int k8 = 0; k8 < 8; ++k8){
        uint4 av = *(const uint4*)(Ap + k8 * 8);
        unsigned pr[4] = {av.x, av.y, av.z, av.w};
#pragma unroll
        for (int pi = 0; pi < 4; ++pi){
          h2v ap = u2h2(pr[pi]);
          const unsigned* wr = Wp + (k8 * 4 + pi) * NOUT;
#pragma unroll
          for (int c = 0; c < NOUT; ++c) acc[c] = dot2(ap, u2h2(wr[c]), acc[c]);
        }
      }
    }
  }
  __syncthreads();
  if (row >= nrows) return;
#pragma unroll
  for (int c = 0; c < NOUT; ++c){
    float b = FOLD ? bfull[c] : bias[ct + c];
    float v = acc[c] + b;
    acc[c] = relu ? fmaxf(v, 0.f) : v;
  }
  unsigned p[NOUT / 2];
#pragma unroll
  for (int c = 0; c < NOUT; c += 2) p[c / 2] = pack2h(acc[c], acc[c + 1]);
  uint4* op = (uint4*)(Ov + (size_t)row * ldo + ct);
#pragma unroll
  for (int i = 0; i < NOUT / 8; ++i) op[i] = make_uint4(p[4*i], p[4*i+1], p[4*i+2], p[4*i+3]);
}

// ---------------- passA (FLAT dst-sorted edges, 16-edge batches): BN1 stats, block-reduced atomics ----------------
__global__ __launch_bounds__(256) void passA_kernel(const hfr* __restrict__ P, const hfr* __restrict__ Q,
                                                    const int* __restrict__ ssrc, const int* __restrict__ sdst,
                                                    float* __restrict__ stats, int E){
  const int lane = threadIdx.x & 63;
  const int wid = (blockIdx.x * 256 + threadIdx.x) >> 6;
  const int nw = (gridDim.x * 256) >> 6;
  const _Float16 z16 = (_Float16)0;
  const int lim = E - 1;
  float sum = 0.f, sq = 0.f;
  for (int base = wid * 16; base < E; base += nw * 16){
    int idx = min(base + (lane & 15), lim);
    int sv = ssrc[idx];
    int dv = sdst[idx];
#pragma unroll
    for (int j = 0; j < 16; ++j){
      int sj = __shfl(sv, j, 64);
      int dj = __shfl(dv, j, 64);
      _Float16 a = asH(P[(size_t)dj * 64 + lane]) + asH(Q[(size_t)sj * 64 + lane]);
      float v = (a < z16) ? 0.f : (float)a;
      bool valid = (base + j) < E;
      sum += valid ? v : 0.f;
      sq  += valid ? v * v : 0.f;
    }
  }
  // block-level reduction: 1 wave of same-line atomics per BLOCK
  __shared__ float ls[256], lq[256];
  ls[threadIdx.x] = sum; lq[threadIdx.x] = sq;
  __syncthreads();
  if (threadIdx.x < 64){
    int c = threadIdx.x;
    atomicAdd(&stats[c], ls[c] + ls[64 + c] + ls[128 + c] + ls[192 + c]);
  } else if (threadIdx.x < 128){
    int c = threadIdx.x - 64;
    atomicAdd(&stats[64 + c], lq[c] + lq[64 + c] + lq[128 + c] + lq[192 + c]);
  }
}

// ---------------- passBC: inlined BN1 fold + MFMA 16-edge batches + BN2 stats (block-reduced) + register segment-max ----------------
// A[m=lane&15][k=quad*8+j] (verified m120); C[col=lane&15][row=quad*4+reg] (verified m89).
__global__ __launch_bounds__(256) void passBC_kernel(const hfr* __restrict__ P, const hfr* __restrict__ Q,
                                                     const int* __restrict__ ssrc, const int* __restrict__ row_off,
                                                     const float* __restrict__ statsIn, float Einv,
                                                     const float* __restrict__ g1, const float* __restrict__ be1,
                                                     const float* __restrict__ Wb, const float* __restrict__ bn,
                                                     float* __restrict__ agg, float* __restrict__ statsOut, int N){
  __shared__ _Float16 W2T[64 * 72];     // [c][k] = (f16)(a1[k]*Wb[k][c]), padded
  __shared__ _Float16 ht[4][16][72];    // per-wave 16-edge h1 tile, padded
  __shared__ float aS[64], bbS[64], b2S[64], bsum[256], qsum[256];
  const int tid = threadIdx.x;
  const int lane = tid & 63;
  const int half = lane >> 5;
  const int cl = lane & 31;
  const int wib = tid >> 6;
  const _Float16 z16 = (_Float16)0;
  if (tid < 64){
    float mu = statsIn[tid] * Einv;
    float var = statsIn[64 + tid] * Einv - mu * mu;
    float ai = g1[tid] * rsqrtf(var + EPS);
    aS[tid] = ai; bbS[tid] = be1[tid] - ai * mu;
  }
  __syncthreads();
  for (int i = tid; i < 4096; i += 256){
    int c = i >> 6, k = i & 63;
    W2T[c * 72 + k] = (_Float16)(aS[k] * Wb[(size_t)k * 64 + c]);
  }
  {
    int c = tid & 63, p = tid >> 6;   // parts = 4
    float s = 0.f;
    for (int k = p; k < 64; k += 4) s += bbS[k] * Wb[(size_t)k * 64 + c];
    bsum[p * 64 + c] = s;
  }
  __syncthreads();
  if (tid < 64) b2S[tid] = bn[tid] + bsum[tid] + bsum[64 + tid] + bsum[128 + tid] + bsum[192 + tid];
  __syncthreads();
  f16x8 Bf[4][2];
#pragma unroll
  for (int t = 0; t < 4; ++t)
#pragma unroll
    for (int h = 0; h < 2; ++h){
      int c = t * 16 + (lane & 15);
      Bf[t][h] = *(const f16x8*)&W2T[c * 72 + h * 32 + (lane >> 4) * 8];
    }
  float bc[4];
#pragma unroll
  for (int t = 0; t < 4; ++t) bc[t] = b2S[t * 16 + (lane & 15)];
  _Float16 (*hl)[72] = ht[wib];
  const int wid = (blockIdx.x * 256 + tid) >> 6;
  const int nw = (gridDim.x * 256) >> 6;
  float sumT[4] = {0.f,0.f,0.f,0.f}, sqT[4] = {0.f,0.f,0.f,0.f};
  for (int n = wid; n < N; n += nw){
    const int e0 = row_off[n], e1 = row_off[n + 1];
    if (e0 >= e1) continue;
    unsigned pw = *(const unsigned*)(P + (size_t)n * 64 + 2 * cl);
    h2v pv2 = u2h2(pw);
    const int lim = e1 - 1;
    float mxT[4] = {0.f,0.f,0.f,0.f};
    for (int eb = e0; eb < e1; eb += 16){
      int sv = ssrc[min(eb + (lane & 15), lim)];
#pragma unroll
      for (int t = 0; t < 8; ++t){           // half-wave: 2 rows/step, 16 gathers in flight
        int j = 2 * t + half;
        int sj = __shfl(sv, j, 64);
        unsigned qw = *(const unsigned*)(Q + (size_t)sj * 64 + 2 * cl);
        h2v s = pv2 + u2h2(qw);
        s.x = (s.x < z16) ? z16 : s.x;
        s.y = (s.y < z16) ? z16 : s.y;
        *(unsigned*)&hl[j][2 * cl] = h22u(s);
      }
      // intra-wave LDS RAW: compiler emits lgkmcnt wait, no barrier needed
      f16x8 A0 = *(const f16x8*)&hl[lane & 15][(lane >> 4) * 8];
      f16x8 A1 = *(const f16x8*)&hl[lane & 15][32 + (lane >> 4) * 8];
#pragma unroll
      for (int t = 0; t < 4; ++t){
        f32x4 Cv = {bc[t], bc[t], bc[t], bc[t]};
        Cv = __builtin_amdgcn_mfma_f32_16x16x32_f16(A0, Bf[t][0], Cv, 0, 0, 0);
        Cv = __builtin_amdgcn_mfma_f32_16x16x32_f16(A1, Bf[t][1], Cv, 0, 0, 0);
#pragma unroll
        for (int r = 0; r < 4; ++r){
          float v = fmaxf(Cv[r], 0.f);
          int rowi = (lane >> 4) * 4 + r;
          bool valid = (eb + rowi) < e1;
          mxT[t] = fmaxf(mxT[t], v);          // clamped dup rows mirror a real edge: max-safe
          sumT[t] += valid ? v : 0.f;
          sqT[t]  += valid ? v * v : 0.f;
        }
      }
    }
#pragma unroll
    for (int t = 0; t < 4; ++t){
      float m = mxT[t];
      m = fmaxf(m, __shfl_xor(m, 16, 64));
      m = fmaxf(m, __shfl_xor(m, 32, 64));
      mxT[t] = m;
    }
    float outv = (lane < 16) ? mxT[0] : (lane < 32) ? mxT[1] : (lane < 48) ? mxT[2] : mxT[3];
    agg[(size_t)n * 64 + lane] = outv;
  }
#pragma unroll
  for (int t = 0; t < 4; ++t){
    float s = sumT[t], q = sqT[t];
    s += __shfl_xor(s, 16, 64); s += __shfl_xor(s, 32, 64);
    q += __shfl_xor(q, 16, 64); q += __shfl_xor(q, 32, 64);
    sumT[t] = s; sqT[t] = q;
  }
  float ssel = (lane < 16) ? sumT[0] : (lane < 32) ? sumT[1] : (lane < 48) ? sumT[2] : sumT[3];
  float qsel = (lane < 16) ? sqT[0]  : (lane < 32) ? sqT[1]  : (lane < 48) ? sqT[2]  : sqT[3];
  // block-level reduction: 1 wave of same-line atomics per BLOCK
  bsum[tid] = ssel; qsum[tid] = qsel;
  __syncthreads();
  if (tid < 64){
    atomicAdd(&statsOut[tid], bsum[tid] + bsum[64 + tid] + bsum[128 + tid] + bsum[192 + tid]);
  } else if (tid < 128){
    int c = tid - 64;
    atomicAdd(&statsOut[64 + c], qsum[c] + qsum[64 + c] + qsum[128 + c] + qsum[192 + c]);
  }
}

// ---------------- fixup with inlined BN2 coefficients ----------------
__global__ __launch_bounds__(256) void fixup_kernel(const float* __restrict__ agg, const int* __restrict__ deg,
                                                    const float* __restrict__ stats, float cntInv,
                                                    const float* __restrict__ g, const float* __restrict__ be,
                                                    hfr* __restrict__ xout, int ldx, int N){
  int t = blockIdx.x * 256 + threadIdx.x;
  if (t >= N * 64) return;
  int n = t >> 6, c = t & 63;
  float mu = stats[c] * cntInv;
  float var = stats[64 + c] * cntInv - mu * mu;
  float a = g[c] * rsqrtf(var + EPS);
  float b = be[c] - a * mu;
  float v = 0.f;
  if (deg[n] > 0) v = a * agg[t] + b;
  xout[(size_t)n * ldx + c] = f2h(v);
}

// ---------------- node BN stats over f16 activations ----------------
template<int C>
__global__ __launch_bounds__(256) void statsN_kernel(const hfr* __restrict__ u, float* __restrict__ stats, int N){
  constexpr int RP = 256 / C;
  const int c = threadIdx.x % C, j = threadIdx.x / C;
  float sum = 0.f, sq = 0.f;
  for (int r = blockIdx.x * RP + j; r < N; r += gridDim.x * RP){
    float v = h2f(u[(size_t)r * C + c]);
    sum += v; sq += v * v;
  }
  __shared__ float ls[256], lq[256];
  ls[threadIdx.x] = sum; lq[threadIdx.x] = sq;
  __syncthreads();
  if (threadIdx.x < C){
    float s = 0.f, q = 0.f;
#pragma unroll
    for (int jj = 0; jj < RP; ++jj){ s += ls[jj * C + c]; q += lq[jj * C + c]; }
    atomicAdd(&stats[c], s); atomicAdd(&stats[C + c], q);
  }
}

// ---------------- head: inlined BN fold + logits + log_softmax ----------------
__global__ __launch_bounds__(256) void head_kernel(const hfr* __restrict__ u2,
                                                   const float* __restrict__ stats, float cntInv,
                                                   const float* __restrict__ g, const float* __restrict__ be,
                                                   const float* __restrict__ Wo, const float* __restrict__ bo,
                                                   void* __restrict__ out, int N, const int* __restrict__ flag){
  __shared__ float Ws[32 * 24];
  __shared__ float bs[24];
  __shared__ float aS[32], bbS[32];
  const int tid = threadIdx.x;
  if (tid < 32){
    float mu = stats[tid] * cntInv;
    float var = stats[32 + tid] * cntInv - mu * mu;
    float ai = g[tid] * rsqrtf(var + EPS);
    aS[tid] = ai; bbS[tid] = be[tid] - ai * mu;
  }
  __syncthreads();
  for (int i = tid; i < 32 * 24; i += 256){
    int k = i / 24, c = i - 24 * k;
    Ws[i] = aS[k] * Wo[(size_t)k * 24 + c];
  }
  if (tid < 24){
    float t = bo[tid];
    for (int k = 0; k < 32; ++k) t += bbS[k] * Wo[(size_t)k * 24 + tid];
    bs[tid] = t;
  }
  __syncthreads();
  int r = blockIdx.x * 256 + tid;
  if (r >= N) return;
  int isf = *flag;
  float l[24];
#pragma unroll
  for (int c = 0; c < 24; ++c) l[c] = bs[c];
  const hfr* up = u2 + (size_t)r * 32;
#pragma unroll
  for (int k = 0; k < 32; ++k){
    float v = h2f(up[k]);
#pragma unroll
    for (int c = 0; c < 24; ++c) l[c] += v * Ws[k * 24 + c];
  }
  float m = l[0];
#pragma unroll
  for (int c = 1; c < 24; ++c) m = fmaxf(m, l[c]);
  float s = 0.f;
#pragma unroll
  for (int c = 0; c < 24; ++c) s += expf(l[c] - m);
  float lse = m + logf(s);
  if (isf){
    float4* op = (float4*)((float*)out + (size_t)r * 24);
#pragma unroll
    for (int i = 0; i < 6; ++i)
      op[i] = make_float4(l[4*i] - lse, l[4*i+1] - lse, l[4*i+2] - lse, l[4*i+3] - lse);
  } else {
    unsigned p[12];
#pragma unroll
    for (int c = 0; c < 24; c += 2) p[c / 2] = pack2bf(l[c] - lse, l[c + 1] - lse);
    uint4* op = (uint4*)((bfr*)out + (size_t)r * 24);
#pragma unroll
    for (int i = 0; i < 3; ++i) op[i] = make_uint4(p[4*i], p[4*i+1], p[4*i+2], p[4*i+3]);
  }
}

// ---------------- host ----------------
// ROUND-15: exact revert to the round-13 configuration (988 µs empirical best):
// GWA/GWB=1024, passA 16-edge flat batches. Round-14's occupancy levers both
// regressed (prologue amortization dominates; occupancy capped elsewhere).
extern "C" void kernel_launch(void* const* d_in, const int* in_sizes, int n_in,
                              void* d_out, int out_size, void* d_ws, size_t ws_size,
                              hipStream_t stream){
  const int N = in_sizes[0] / 6;
  const int E = in_sizes[31] / 2;
  const int* edge = (const int*)d_in[31];
  const int* src = edge;
  const int* dst = edge + E;

  size_t off = 0; char* basep = (char*)d_ws;
  auto alloc = [&](size_t bytes) -> void* {
    void* p = basep + off;
    off = (off + bytes + 255) & ~(size_t)255;
    return p;
  };
  float* stA  = (float*)alloc(1472 * 4);
  float* stN1 = stA + 768;
  float* stN2 = stA + 1280;
  float* stN3 = stA + 1408;
  int*   flag = (int*)  alloc(4);
  int*   deg  = (int*)  alloc((size_t)N * 4);
  int*   rowo = (int*)  alloc((size_t)(N + 1) * 4);
  int*   cur  = (int*)  alloc((size_t)N * 4);
  int*   loco = (int*)  alloc((size_t)N * 4);
  int*   bsc  = (int*)  alloc(1024 * 4);
  int*   ssrc = (int*)  alloc((size_t)E * 4);
  int*   sdst = (int*)  alloc((size_t)E * 4);

  ParamPtrs pp; ParamOfs po;
  int hoff[32]; int total = 0;
  for (int s = 0; s < NPAR; ++s){
    int idx = (s < 30) ? (s + 1) : 0;
    pp.p[s] = d_in[idx];
    po.off[s] = total;
    hoff[idx] = total;
    total += in_sizes[idx];
  }
  po.off[NPAR] = total;
  float* pf = (float*)alloc((size_t)total * 4);

  hfr*   P    = (hfr*)  alloc((size_t)N * 64 * 2);
  hfr*   Qb   = (hfr*)  alloc((size_t)N * 64 * 2);
  float* agg  = (float*)alloc((size_t)N * 64 * 4);
  hfr*   xcat = (hfr*)  alloc((size_t)N * 192 * 2);
  hfr* u_l = (hfr*)P;                 // [N,256] f16 over P+Q+agg
  hfr* u1  = xcat;                    // [N,64]  f16
  hfr* u2  = xcat + (size_t)N * 64;   // [N,32]  f16
  (void)ws_size; (void)n_in; (void)out_size;

  dim3 B(256);
  detect_kernel<<<1, B, 0, stream>>>((const bfr*)d_in[0], 256, flag);
  acvt_batch_kernel<<<cdiv(total, 256), B, 0, stream>>>(pp, po, pf, total, flag);

  hipMemsetAsync(stA, 0, 1472 * 4, stream);
  hipMemsetAsync(deg, 0, (size_t)N * 4, stream);
  deg_kernel<<<cdiv(E, 256), B, 0, stream>>>(dst, deg, E);
  const int NBn = cdiv(N, 256);
  scan1_kernel<<<NBn, B, 0, stream>>>(deg, loco, bsc, N);
  scan2_kernel<<<1, B, 0, stream>>>(bsc, NBn);
  scan3_kernel<<<NBn, B, 0, stream>>>(loco, bsc, rowo, cur, N, E);
  scatter_kernel<<<cdiv(E, 256), B, 0, stream>>>(src, dst, cur, ssrc, sdst, E);

  const int NB = cdiv(N, 256);
  const int GWA = 1024, GWB = 1024;
  const float Einv = 1.f / (float)E;
  for (int k = 0; k < 3; ++k){
    const float *Wa_k, *ba_k, *ga_k, *bea_k, *Wb_k, *bb_k, *gb_k, *beb_k;
    if (k == 0){
      Wa_k = pf + hoff[1]; ba_k = pf + hoff[2]; ga_k = pf + hoff[3]; bea_k = pf + hoff[4];
      Wb_k = pf + hoff[5]; bb_k = pf + hoff[6]; gb_k = pf + hoff[7]; beb_k = pf + hoff[8];
    } else {
      int kk = k - 1;
      Wa_k = pf + hoff[9]  + (size_t)kk * 128 * 64;
      ba_k = pf + hoff[10] + kk * 64;
      ga_k = pf + hoff[11] + kk * 64;
      bea_k= pf + hoff[12] + kk * 64;
      Wb_k = pf + hoff[13] + (size_t)kk * 64 * 64;
      bb_k = pf + hoff[14] + kk * 64;
      gb_k = pf + hoff[15] + kk * 64;
      beb_k= pf + hoff[16] + kk * 64;
    }
    float* st1 = stA + k * 256;
    float* st2 = st1 + 128;
    if (k == 0)
      gemmPQ_kernel<true><<<dim3(NB, 2), B, 0, stream>>>(pf + hoff[0], 6, Wa_k, 6, ba_k, P, Qb, N);
    else
      gemmPQ_kernel<false><<<dim3(NB, 2), B, 0, stream>>>(xcat + (size_t)(k - 1) * 64, 192, Wa_k, 64, ba_k, P, Qb, N);
    passA_kernel<<<GWA, B, 0, stream>>>(P, Qb, ssrc, sdst, st1, E);
    passBC_kernel<<<GWB, B, 0, stream>>>(P, Qb, ssrc, rowo, st1, Einv, ga_k, bea_k, Wb_k, bb_k,
                                         agg, st2, N);
    fixup_kernel<<<cdiv(N * 64, 256), B, 0, stream>>>(agg, deg, st2, Einv, gb_k, beb_k,
                                                      xcat + (size_t)k * 64, 192, N);
  }

  // node MLP (folds inlined into consuming GEMMs / head)
  gemm_kernel<64, false><<<dim3(NB, 4), B, 0, stream>>>(xcat, 192, pf + hoff[17], 256, pf + hoff[18],
                                                        nullptr, 0.f, nullptr, nullptr,
                                                        u_l, 256, N, 192, 1);
  statsN_kernel<256><<<512, B, 0, stream>>>(u_l, stN1, N);
  gemm_kernel<64, true><<<dim3(NB, 1), B, 0, stream>>>(u_l, 256, pf + hoff[21], 64, pf + hoff[22],
                                                       stN1, 1.f / (float)N, pf + hoff[19], pf + hoff[20],
                                                       u1, 64, N, 256, 1);
  statsN_kernel<64><<<512, B, 0, stream>>>(u1, stN2, N);
  gemm_kernel<32, true><<<dim3(NB, 1), B, 0, stream>>>(u1, 64, pf + hoff[25], 32, pf + hoff[26],
                                                       stN2, 1.f / (float)N, pf + hoff[23], pf + hoff[24],
                                                       u2, 32, N, 64, 1);
  statsN_kernel<32><<<512, B, 0, stream>>>(u2, stN3, N);
  head_kernel<<<cdiv(N, 256), B, 0, stream>>>(u2, stN3, 1.f / (float)N, pf + hoff[27], pf + hoff[28],
                                              pf + hoff[29], pf + hoff[30], d_out, N, flag);
}

// Round 16
// 885.967 us; speedup vs baseline: 1.3204x; 1.1737x over previous
//
#include <hip/hip_runtime.h>
#include <hip/hip_bf16.h>

#define EPS 1e-5f
typedef unsigned short bfr;   // raw bf16 bits
typedef unsigned short hfr;   // raw f16 bits
typedef _Float16 h2v __attribute__((ext_vector_type(2)));
typedef _Float16 f16x8 __attribute__((ext_vector_type(8)));
typedef float f32x4 __attribute__((ext_vector_type(4)));

#if defined(__has_builtin)
#if __has_builtin(__builtin_amdgcn_fdot2)
#define HAS_FDOT2 1
#endif
#endif

static inline int cdiv(int a, int b){ return (a + b - 1) / b; }

__device__ __forceinline__ float bf2f(bfr u){ return __uint_as_float((unsigned)u << 16); }
__device__ __forceinline__ bfr f2bf(float f){
  unsigned u = __float_as_uint(f);
  u += 0x7fffu + ((u >> 16) & 1u);
  return (bfr)(u >> 16);
}
__device__ __forceinline__ unsigned pack2bf(float a, float b){
  return (unsigned)f2bf(a) | ((unsigned)f2bf(b) << 16);
}
__device__ __forceinline__ float h2f(hfr u){ _Float16 h; __builtin_memcpy(&h, &u, 2); return (float)h; }
__device__ __forceinline__ _Float16 asH(hfr u){ _Float16 h; __builtin_memcpy(&h, &u, 2); return h; }
__device__ __forceinline__ hfr f2h(float f){ _Float16 h = (_Float16)f; hfr u; __builtin_memcpy(&u, &h, 2); return u; }
__device__ __forceinline__ unsigned pack2h(float a, float b){
  return (unsigned)f2h(a) | ((unsigned)f2h(b) << 16);
}
__device__ __forceinline__ h2v u2h2(unsigned u){ h2v r; __builtin_memcpy(&r, &u, 4); return r; }
__device__ __forceinline__ unsigned h22u(h2v h){ unsigned u; __builtin_memcpy(&u, &h, 4); return u; }
__device__ __forceinline__ float dot2(h2v a, h2v b, float c){
#ifdef HAS_FDOT2
  return __builtin_amdgcn_fdot2(a, b, c, false);
#else
  return c + (float)a.x * (float)b.x + (float)a.y * (float)b.y;
#endif
}

// ---------------- dtype detection (bf16 vs f32 inputs) ----------------
__global__ __launch_bounds__(256) void detect_kernel(const bfr* __restrict__ xr, int nwords, int* __restrict__ flag){
  int i = threadIdx.x;
  int bad = 0;
  if (i < nwords){
    bfr lo = xr[2 * i];
    int e = (lo >> 7) & 0xFF;
    bool plausible = ((lo & 0x7FFF) == 0) || (e >= 97 && e <= 157);
    bad = plausible ? 0 : 1;
  }
  __shared__ int s[256];
  s[threadIdx.x] = bad; __syncthreads();
  for (int st = 128; st; st >>= 1){
    if (threadIdx.x < st) s[threadIdx.x] += s[threadIdx.x + st];
    __syncthreads();
  }
  if (threadIdx.x == 0) *flag = (s[0] > 32) ? 1 : 0;
}

// ---------------- batched adaptive convert ----------------
#define NPAR 31
struct ParamPtrs { const void* p[NPAR]; };
struct ParamOfs  { int off[NPAR + 1]; };

__global__ __launch_bounds__(256) void acvt_batch_kernel(ParamPtrs pp, ParamOfs po,
                                                         float* __restrict__ out, int total,
                                                         const int* __restrict__ flag){
  int g = blockIdx.x * 256 + threadIdx.x;
  if (g >= total) return;
  int isf = *flag;
  int t = 0;
  while (po.off[t + 1] <= g) ++t;
  int i = g - po.off[t];
  out[g] = isf ? ((const float*)pp.p[t])[i] : bf2f(((const bfr*)pp.p[t])[i]);
}

// ---------------- counting sort of edges by dst (multi-block scan) ----------------
__global__ __launch_bounds__(256) void deg_kernel(const int* __restrict__ dst, int* __restrict__ deg, int E){
  int e = blockIdx.x * 256 + threadIdx.x;
  if (e < E) atomicAdd(&deg[dst[e]], 1);
}

__global__ __launch_bounds__(256) void scan1_kernel(const int* __restrict__ deg, int* __restrict__ locoff,
                                                    int* __restrict__ bsum, int N){
  __shared__ int s[256];
  int i = blockIdx.x * 256 + threadIdx.x;
  int v = (i < N) ? deg[i] : 0;
  s[threadIdx.x] = v; __syncthreads();
  for (int st = 1; st < 256; st <<= 1){
    int u = (threadIdx.x >= st) ? s[threadIdx.x - st] : 0;
    __syncthreads();
    s[threadIdx.x] += u;
    __syncthreads();
  }
  if (i < N) locoff[i] = s[threadIdx.x] - v;
  if (threadIdx.x == 255) bsum[blockIdx.x] = s[255];
}

__global__ __launch_bounds__(256) void scan2_kernel(int* __restrict__ bsum, int nb){
  __shared__ int s[256];
  const int t = threadIdx.x;
  int carry = 0;
  for (int base = 0; base < nb; base += 256){
    int v = (base + t < nb) ? bsum[base + t] : 0;
    s[t] = v; __syncthreads();
    for (int st = 1; st < 256; st <<= 1){
      int u = (t >= st) ? s[t - st] : 0;
      __syncthreads();
      s[t] += u;
      __syncthreads();
    }
    if (base + t < nb) bsum[base + t] = carry + s[t] - v;
    carry += s[255];
    __syncthreads();
  }
}

__global__ __launch_bounds__(256) void scan3_kernel(const int* __restrict__ locoff, const int* __restrict__ bsum,
                                                    int* __restrict__ row_off, int* __restrict__ cur,
                                                    int N, int E){
  int i = blockIdx.x * 256 + threadIdx.x;
  if (i < N){
    int v = locoff[i] + bsum[blockIdx.x];
    row_off[i] = v; cur[i] = v;
  }
  if (i == 0) row_off[N] = E;
}

__global__ __launch_bounds__(256) void scatter_kernel(const int* __restrict__ src, const int* __restrict__ dst,
                                                      int* __restrict__ cur, int* __restrict__ ssrc,
                                                      int* __restrict__ sdst, int E){
  int e = blockIdx.x * 256 + threadIdx.x;
  if (e < E){
    int d = dst[e];
    int p = atomicAdd(&cur[d], 1);
    ssrc[p] = src[e];
    sdst[p] = d;
  }
}

// ---------------- fused P/Q GEMM: y=0 -> P = A@(Wtop-Wbot)+ba ; y=1 -> Q = A@Wbot ----------------
template<bool FIRST>
__global__ __launch_bounds__(256) void gemmPQ_kernel(const void* __restrict__ Av, int lda,
                                                     const float* __restrict__ Wa, int d,
                                                     const float* __restrict__ ba,
                                                     hfr* __restrict__ P, hfr* __restrict__ Q, int N){
  __shared__ unsigned WsU[64 * 64];
  const int y = blockIdx.y;
  const int tot = d * 64;
  if (FIRST){
    float* Ws = (float*)WsU;
    for (int i = threadIdx.x; i < tot; i += 256)
      Ws[i] = y ? Wa[tot + i] : (Wa[i] - Wa[tot + i]);
  } else {
    for (int i = threadIdx.x; i < 32 * 64; i += 256){
      int p = i >> 6, c = i & 63;
      int i0 = (2 * p) * 64 + c, i1 = (2 * p + 1) * 64 + c;
      float w0 = y ? Wa[tot + i0] : (Wa[i0] - Wa[tot + i0]);
      float w1 = y ? Wa[tot + i1] : (Wa[i1] - Wa[tot + i1]);
      WsU[i] = pack2h(w0, w1);
    }
  }
  __syncthreads();
  const int row = blockIdx.x * 256 + threadIdx.x;
  if (row >= N) return;
  float acc[64];
#pragma unroll
  for (int c = 0; c < 64; ++c) acc[c] = 0.f;
  if (FIRST){
    const float* Ws = (const float*)WsU;
    const float* Af = (const float*)Av + (size_t)row * lda;
    for (int k = 0; k < d; ++k){
      float a = Af[k];
      const float* wr = Ws + k * 64;
#pragma unroll
      for (int c4 = 0; c4 < 16; ++c4){
        float4 w = *(const float4*)(wr + 4 * c4);
        acc[4*c4+0] += a * w.x; acc[4*c4+1] += a * w.y;
        acc[4*c4+2] += a * w.z; acc[4*c4+3] += a * w.w;
      }
    }
  } else {
    const hfr* Ah = (const hfr*)Av + (size_t)row * lda;
#pragma unroll
    for (int k8 = 0; k8 < 8; ++k8){
      uint4 av = *(const uint4*)(Ah + k8 * 8);
      unsigned pr[4] = {av.x, av.y, av.z, av.w};
#pragma unroll
      for (int pi = 0; pi < 4; ++pi){
        h2v ap = u2h2(pr[pi]);
        const unsigned* wr = WsU + (k8 * 4 + pi) * 64;
#pragma unroll
        for (int c = 0; c < 64; ++c) acc[c] = dot2(ap, u2h2(wr[c]), acc[c]);
      }
    }
  }
  if (!y){
#pragma unroll
    for (int c = 0; c < 64; ++c) acc[c] += ba[c];
  }
  unsigned p[32];
#pragma unroll
  for (int c = 0; c < 64; c += 2) p[c / 2] = pack2h(acc[c], acc[c + 1]);
  hfr* outp = (y ? Q : P) + (size_t)row * 64;
  uint4* op = (uint4*)outp;
#pragma unroll
  for (int i = 0; i < 8; ++i) op[i] = make_uint4(p[4*i], p[4*i+1], p[4*i+2], p[4*i+3]);
}

// ---------------- generic row-per-thread GEMM (MLP; A f16, K mult of 64), optional inlined BN fold ----------------
template<int NOUT, bool FOLD>
__global__ __launch_bounds__(256) void gemm_kernel(const hfr* __restrict__ Ah, int lda,
                                                   const float* __restrict__ W, int ldw,
                                                   const float* __restrict__ bias,
                                                   const float* __restrict__ stats, float cntInv,
                                                   const float* __restrict__ g, const float* __restrict__ be,
                                                   hfr* __restrict__ Ov, int ldo,
                                                   int nrows, int K, int relu){
  __shared__ unsigned Wp[32 * NOUT];
  __shared__ float aS[256], bbS[256], bfull[NOUT], bsum[256];
  const int ct = blockIdx.y * NOUT;
  const int tid = threadIdx.x;
  if (FOLD){
    for (int k = tid; k < K; k += 256){
      float mu = stats[k] * cntInv;
      float var = stats[K + k] * cntInv - mu * mu;
      float ai = g[k] * rsqrtf(var + EPS);
      aS[k] = ai; bbS[k] = be[k] - ai * mu;
    }
    __syncthreads();
    constexpr int parts = 256 / NOUT;
    int c = tid % NOUT, p = tid / NOUT;
    float s = 0.f;
    for (int k = p; k < K; k += parts) s += bbS[k] * W[(size_t)k * ldw + ct + c];
    bsum[p * NOUT + c] = s;
    __syncthreads();
    if (tid < NOUT){
      float t = bias[ct + tid];
#pragma unroll
      for (int pp = 0; pp < parts; ++pp) t += bsum[pp * NOUT + tid];
      bfull[tid] = t;
    }
  }
  const int row = blockIdx.x * 256 + tid;
  float acc[NOUT];
#pragma unroll
  for (int c = 0; c < NOUT; ++c) acc[c] = 0.f;
  for (int k0 = 0; k0 < K; k0 += 64){
    __syncthreads();
    for (int i = tid; i < 32 * NOUT; i += 256){
      int p = i / NOUT, c = i - p * NOUT;
      float w0 = W[(size_t)(k0 + 2 * p) * ldw + ct + c];
      float w1 = W[(size_t)(k0 + 2 * p + 1) * ldw + ct + c];
      if (FOLD){ w0 *= aS[k0 + 2 * p]; w1 *= aS[k0 + 2 * p + 1]; }
      Wp[i] = pack2h(w0, w1);
    }
    __syncthreads();
    if (row < nrows){
      const hfr* Ap = Ah + (size_t)row * lda + k0;
#pragma unroll
      for (int k8 = 0; k8 < 8; ++k8){
        uint4 av = *(const uint4*)(Ap + k8 * 8);
        unsigned pr[4] = {av.x, av.y, av.z, av.w};
#pragma unroll
        for (int pi = 0; pi < 4; ++pi){
          h2v ap = u2h2(pr[pi]);
          const unsigned* wr = Wp + (k8 * 4 + pi) * NOUT;
#pragma unroll
          for (int c = 0; c < NOUT; ++c) acc[c] = dot2(ap, u2h2(wr[c]), acc[c]);
        }
      }
    }
  }
  __syncthreads();
  if (row >= nrows) return;
#pragma unroll
  for (int c = 0; c < NOUT; ++c){
    float b = FOLD ? bfull[c] : bias[ct + c];
    float v = acc[c] + b;
    acc[c] = relu ? fmaxf(v, 0.f) : v;
  }
  unsigned p[NOUT / 2];
#pragma unroll
  for (int c = 0; c < NOUT; c += 2) p[c / 2] = pack2h(acc[c], acc[c + 1]);
  uint4* op = (uint4*)(Ov + (size_t)row * ldo + ct);
#pragma unroll
  for (int i = 0; i < NOUT / 8; ++i) op[i] = make_uint4(p[4*i], p[4*i+1], p[4*i+2], p[4*i+3]);
}

// ---------------- passA (FLAT dst-sorted edges, FAT gathers: 8 rows/instruction) ----------------
// Lane i handles edge eb+(i>>3), 16B chunk (i&7): one dwordx4 load fetches 8 different rows.
__global__ __launch_bounds__(256) void passA_kernel(const hfr* __restrict__ P, const hfr* __restrict__ Q,
                                                    const int* __restrict__ ssrc, const int* __restrict__ sdst,
                                                    float* __restrict__ stats, int E){
  const int tid = threadIdx.x;
  const int lane = tid & 63;
  const int wib = tid >> 6;
  const int er0 = lane >> 3;      // edge sub-index 0..7
  const int ck = lane & 7;        // 16B chunk 0..7 -> channels ck*8..ck*8+7
  const int wid = (blockIdx.x * 256 + tid) >> 6;
  const int nw = (gridDim.x * 256) >> 6;
  const _Float16 z16 = (_Float16)0;
  const int lim = E - 1;
  float s8[8], q8[8];
#pragma unroll
  for (int j = 0; j < 8; ++j){ s8[j] = 0.f; q8[j] = 0.f; }
  for (int base = wid * 16; base < E; base += nw * 16){
    int idx = min(base + (lane & 15), lim);
    int sv = ssrc[idx];
    int dv = sdst[idx];
#pragma unroll
    for (int h = 0; h < 2; ++h){
      int er = h * 8 + er0;
      bool valid = (base + er) < E;
      int sj = __shfl(sv, er, 64);
      int dj = __shfl(dv, er, 64);
      uint4 qv = *((const uint4*)(Q + (size_t)sj * 64) + ck);
      uint4 pv = *((const uint4*)(P + (size_t)dj * 64) + ck);
      unsigned qa[4] = {qv.x, qv.y, qv.z, qv.w};
      unsigned pa[4] = {pv.x, pv.y, pv.z, pv.w};
#pragma unroll
      for (int t = 0; t < 4; ++t){
        h2v sm = u2h2(qa[t]) + u2h2(pa[t]);
        float v0 = (sm.x < z16) ? 0.f : (float)sm.x;
        float v1 = (sm.y < z16) ? 0.f : (float)sm.y;
        v0 = valid ? v0 : 0.f; v1 = valid ? v1 : 0.f;
        s8[2*t]   += v0; q8[2*t]   += v0 * v0;
        s8[2*t+1] += v1; q8[2*t+1] += v1 * v1;
      }
    }
  }
  // reduce across the 8 lanes sharing chunk ck (bits 3..5 vary): xor 8,16,32
#pragma unroll
  for (int j = 0; j < 8; ++j){
    float s = s8[j], q = q8[j];
    s += __shfl_xor(s, 8, 64);  q += __shfl_xor(q, 8, 64);
    s += __shfl_xor(s, 16, 64); q += __shfl_xor(q, 16, 64);
    s += __shfl_xor(s, 32, 64); q += __shfl_xor(q, 32, 64);
    s8[j] = s; q8[j] = q;
  }
  __shared__ float ls[4][64], lq[4][64];
  if (lane < 8){
#pragma unroll
    for (int j = 0; j < 8; ++j){ ls[wib][lane * 8 + j] = s8[j]; lq[wib][lane * 8 + j] = q8[j]; }
  }
  __syncthreads();
  if (tid < 64){
    atomicAdd(&stats[tid], ls[0][tid] + ls[1][tid] + ls[2][tid] + ls[3][tid]);
  } else if (tid < 128){
    int c = tid - 64;
    atomicAdd(&stats[64 + c], lq[0][c] + lq[1][c] + lq[2][c] + lq[3][c]);
  }
}

// ---------------- passBC: inlined BN1 fold + FAT-gather staging + MFMA + BN2 stats + register segment-max ----------------
// A[m=lane&15][k=quad*8+j] (verified m120); C[col=lane&15][row=quad*4+reg] (verified m89).
__global__ __launch_bounds__(256) void passBC_kernel(const hfr* __restrict__ P, const hfr* __restrict__ Q,
                                                     const int* __restrict__ ssrc, const int* __restrict__ row_off,
                                                     const float* __restrict__ statsIn, float Einv,
                                                     const float* __restrict__ g1, const float* __restrict__ be1,
                                                     const float* __restrict__ Wb, const float* __restrict__ bn,
                                                     float* __restrict__ agg, float* __restrict__ statsOut, int N){
  __shared__ __align__(16) _Float16 W2T[64 * 72];   // [c][k] = (f16)(a1[k]*Wb[k][c]), padded
  __shared__ __align__(16) _Float16 ht[4][16][72];  // per-wave 16-edge h1 tile, padded (72*2B=144B rows, 16B-mult)
  __shared__ float aS[64], bbS[64], b2S[64], bsum[256], qsum[256];
  const int tid = threadIdx.x;
  const int lane = tid & 63;
  const int er0 = lane >> 3;
  const int ck = lane & 7;
  const int wib = tid >> 6;
  const _Float16 z16 = (_Float16)0;
  if (tid < 64){
    float mu = statsIn[tid] * Einv;
    float var = statsIn[64 + tid] * Einv - mu * mu;
    float ai = g1[tid] * rsqrtf(var + EPS);
    aS[tid] = ai; bbS[tid] = be1[tid] - ai * mu;
  }
  __syncthreads();
  for (int i = tid; i < 4096; i += 256){
    int c = i >> 6, k = i & 63;
    W2T[c * 72 + k] = (_Float16)(aS[k] * Wb[(size_t)k * 64 + c]);
  }
  {
    int c = tid & 63, p = tid >> 6;   // parts = 4
    float s = 0.f;
    for (int k = p; k < 64; k += 4) s += bbS[k] * Wb[(size_t)k * 64 + c];
    bsum[p * 64 + c] = s;
  }
  __syncthreads();
  if (tid < 64) b2S[tid] = bn[tid] + bsum[tid] + bsum[64 + tid] + bsum[128 + tid] + bsum[192 + tid];
  __syncthreads();
  f16x8 Bf[4][2];
#pragma unroll
  for (int t = 0; t < 4; ++t)
#pragma unroll
    for (int h = 0; h < 2; ++h){
      int c = t * 16 + (lane & 15);
      Bf[t][h] = *(const f16x8*)&W2T[c * 72 + h * 32 + (lane >> 4) * 8];
    }
  float bc[4];
#pragma unroll
  for (int t = 0; t < 4; ++t) bc[t] = b2S[t * 16 + (lane & 15)];
  _Float16 (*hl)[72] = ht[wib];
  const int wid = (blockIdx.x * 256 + tid) >> 6;
  const int nw = (gridDim.x * 256) >> 6;
  float sumT[4] = {0.f,0.f,0.f,0.f}, sqT[4] = {0.f,0.f,0.f,0.f};
  for (int n = wid; n < N; n += nw){
    const int e0 = row_off[n], e1 = row_off[n + 1];
    if (e0 >= e1) continue;
    uint4 pv4 = ((const uint4*)(P + (size_t)n * 64))[ck];
    h2v pp0 = u2h2(pv4.x), pp1 = u2h2(pv4.y), pp2 = u2h2(pv4.z), pp3 = u2h2(pv4.w);
    const int lim = e1 - 1;
    float mxT[4] = {0.f,0.f,0.f,0.f};
    for (int eb = e0; eb < e1; eb += 16){
      int sv = ssrc[min(eb + (lane & 15), lim)];
#pragma unroll
      for (int h = 0; h < 2; ++h){           // FAT gather: 8 rows per dwordx4 instruction
        int er = h * 8 + er0;
        int sj = __shfl(sv, er, 64);
        uint4 qv = *((const uint4*)(Q + (size_t)sj * 64) + ck);
        h2v s0 = u2h2(qv.x) + pp0;
        h2v s1 = u2h2(qv.y) + pp1;
        h2v s2 = u2h2(qv.z) + pp2;
        h2v s3 = u2h2(qv.w) + pp3;
        s0.x = (s0.x < z16) ? z16 : s0.x; s0.y = (s0.y < z16) ? z16 : s0.y;
        s1.x = (s1.x < z16) ? z16 : s1.x; s1.y = (s1.y < z16) ? z16 : s1.y;
        s2.x = (s2.x < z16) ? z16 : s2.x; s2.y = (s2.y < z16) ? z16 : s2.y;
        s3.x = (s3.x < z16) ? z16 : s3.x; s3.y = (s3.y < z16) ? z16 : s3.y;
        *(uint4*)&hl[er][ck * 8] = make_uint4(h22u(s0), h22u(s1), h22u(s2), h22u(s3));
      }
      // intra-wave LDS RAW: compiler emits lgkmcnt wait, no barrier needed
      f16x8 A0 = *(const f16x8*)&hl[lane & 15][(lane >> 4) * 8];
      f16x8 A1 = *(const f16x8*)&hl[lane & 15][32 + (lane >> 4) * 8];
#pragma unroll
      for (int t = 0; t < 4; ++t){
        f32x4 Cv = {bc[t], bc[t], bc[t], bc[t]};
        Cv = __builtin_amdgcn_mfma_f32_16x16x32_f16(A0, Bf[t][0], Cv, 0, 0, 0);
        Cv = __builtin_amdgcn_mfma_f32_16x16x32_f16(A1, Bf[t][1], Cv, 0, 0, 0);
#pragma unroll
        for (int r = 0; r < 4; ++r){
          float v = fmaxf(Cv[r], 0.f);
          int rowi = (lane >> 4) * 4 + r;
          bool valid = (eb + rowi) < e1;
          mxT[t] = fmaxf(mxT[t], v);          // clamped dup rows mirror a real edge: max-safe
          sumT[t] += valid ? v : 0.f;
          sqT[t]  += valid ? v * v : 0.f;
        }
      }
    }
#pragma unroll
    for (int t = 0; t < 4; ++t){
      float m = mxT[t];
      m = fmaxf(m, __shfl_xor(m, 16, 64));
      m = fmaxf(m, __shfl_xor(m, 32, 64));
      mxT[t] = m;
    }
    float outv = (lane < 16) ? mxT[0] : (lane < 32) ? mxT[1] : (lane < 48) ? mxT[2] : mxT[3];
    agg[(size_t)n * 64 + lane] = outv;
  }
#pragma unroll
  for (int t = 0; t < 4; ++t){
    float s = sumT[t], q = sqT[t];
    s += __shfl_xor(s, 16, 64); s += __shfl_xor(s, 32, 64);
    q += __shfl_xor(q, 16, 64); q += __shfl_xor(q, 32, 64);
    sumT[t] = s; sqT[t] = q;
  }
  float ssel = (lane < 16) ? sumT[0] : (lane < 32) ? sumT[1] : (lane < 48) ? sumT[2] : sumT[3];
  float qsel = (lane < 16) ? sqT[0]  : (lane < 32) ? sqT[1]  : (lane < 48) ? sqT[2]  : sqT[3];
  // block-level reduction: 1 wave of same-line atomics per BLOCK
  bsum[tid] = ssel; qsum[tid] = qsel;
  __syncthreads();
  if (tid < 64){
    atomicAdd(&statsOut[tid], bsum[tid] + bsum[64 + tid] + bsum[128 + tid] + bsum[192 + tid]);
  } else if (tid < 128){
    int c = tid - 64;
    atomicAdd(&statsOut[64 + c], qsum[c] + qsum[64 + c] + qsum[128 + c] + qsum[192 + c]);
  }
}

// ---------------- fixup with inlined BN2 coefficients ----------------
__global__ __launch_bounds__(256) void fixup_kernel(const float* __restrict__ agg, const int* __restrict__ deg,
                                                    const float* __restrict__ stats, float cntInv,
                                                    const float* __restrict__ g, const float* __restrict__ be,
                                                    hfr* __restrict__ xout, int ldx, int N){
  int t = blockIdx.x * 256 + threadIdx.x;
  if (t >= N * 64) return;
  int n = t >> 6, c = t & 63;
  float mu = stats[c] * cntInv;
  float var = stats[64 + c] * cntInv - mu * mu;
  float a = g[c] * rsqrtf(var + EPS);
  float b = be[c] - a * mu;
  float v = 0.f;
  if (deg[n] > 0) v = a * agg[t] + b;
  xout[(size_t)n * ldx + c] = f2h(v);
}

// ---------------- node BN stats over f16 activations ----------------
template<int C>
__global__ __launch_bounds__(256) void statsN_kernel(const hfr* __restrict__ u, float* __restrict__ stats, int N){
  constexpr int RP = 256 / C;
  const int c = threadIdx.x % C, j = threadIdx.x / C;
  float sum = 0.f, sq = 0.f;
  for (int r = blockIdx.x * RP + j; r < N; r += gridDim.x * RP){
    float v = h2f(u[(size_t)r * C + c]);
    sum += v; sq += v * v;
  }
  __shared__ float ls[256], lq[256];
  ls[threadIdx.x] = sum; lq[threadIdx.x] = sq;
  __syncthreads();
  if (threadIdx.x < C){
    float s = 0.f, q = 0.f;
#pragma unroll
    for (int jj = 0; jj < RP; ++jj){ s += ls[jj * C + c]; q += lq[jj * C + c]; }
    atomicAdd(&stats[c], s); atomicAdd(&stats[C + c], q);
  }
}

// ---------------- head: inlined BN fold + logits + log_softmax ----------------
__global__ __launch_bounds__(256) void head_kernel(const hfr* __restrict__ u2,
                                                   const float* __restrict__ stats, float cntInv,
                                                   const float* __restrict__ g, const float* __restrict__ be,
                                                   const float* __restrict__ Wo, const float* __restrict__ bo,
                                                   void* __restrict__ out, int N, const int* __restrict__ flag){
  __shared__ float Ws[32 * 24];
  __shared__ float bs[24];
  __shared__ float aS[32], bbS[32];
  const int tid = threadIdx.x;
  if (tid < 32){
    float mu = stats[tid] * cntInv;
    float var = stats[32 + tid] * cntInv - mu * mu;
    float ai = g[tid] * rsqrtf(var + EPS);
    aS[tid] = ai; bbS[tid] = be[tid] - ai * mu;
  }
  __syncthreads();
  for (int i = tid; i < 32 * 24; i += 256){
    int k = i / 24, c = i - 24 * k;
    Ws[i] = aS[k] * Wo[(size_t)k * 24 + c];
  }
  if (tid < 24){
    float t = bo[tid];
    for (int k = 0; k < 32; ++k) t += bbS[k] * Wo[(size_t)k * 24 + tid];
    bs[tid] = t;
  }
  __syncthreads();
  int r = blockIdx.x * 256 + tid;
  if (r >= N) return;
  int isf = *flag;
  float l[24];
#pragma unroll
  for (int c = 0; c < 24; ++c) l[c] = bs[c];
  const hfr* up = u2 + (size_t)r * 32;
#pragma unroll
  for (int k = 0; k < 32; ++k){
    float v = h2f(up[k]);
#pragma unroll
    for (int c = 0; c < 24; ++c) l[c] += v * Ws[k * 24 + c];
  }
  float m = l[0];
#pragma unroll
  for (int c = 1; c < 24; ++c) m = fmaxf(m, l[c]);
  float s = 0.f;
#pragma unroll
  for (int c = 0; c < 24; ++c) s += expf(l[c] - m);
  float lse = m + logf(s);
  if (isf){
    float4* op = (float4*)((float*)out + (size_t)r * 24);
#pragma unroll
    for (int i = 0; i < 6; ++i)
      op[i] = make_float4(l[4*i] - lse, l[4*i+1] - lse, l[4*i+2] - lse, l[4*i+3] - lse);
  } else {
    unsigned p[12];
#pragma unroll
    for (int c = 0; c < 24; c += 2) p[c / 2] = pack2bf(l[c] - lse, l[c + 1] - lse);
    uint4* op = (uint4*)((bfr*)out + (size_t)r * 24);
#pragma unroll
    for (int i = 0; i < 3; ++i) op[i] = make_uint4(p[4*i], p[4*i+1], p[4*i+2], p[4*i+3]);
  }
}

// ---------------- host ----------------
// ROUND-16: round-13 structure + FAT gathers in passA/passBC (8 rows per
// dwordx4 instruction, 8x fewer VMEM instructions at identical line traffic).
extern "C" void kernel_launch(void* const* d_in, const int* in_sizes, int n_in,
                              void* d_out, int out_size, void* d_ws, size_t ws_size,
                              hipStream_t stream){
  const int N = in_sizes[0] / 6;
  const int E = in_sizes[31] / 2;
  const int* edge = (const int*)d_in[31];
  const int* src = edge;
  const int* dst = edge + E;

  size_t off = 0; char* basep = (char*)d_ws;
  auto alloc = [&](size_t bytes) -> void* {
    void* p = basep + off;
    off = (off + bytes + 255) & ~(size_t)255;
    return p;
  };
  float* stA  = (float*)alloc(1472 * 4);
  float* stN1 = stA + 768;
  float* stN2 = stA + 1280;
  float* stN3 = stA + 1408;
  int*   flag = (int*)  alloc(4);
  int*   deg  = (int*)  alloc((size_t)N * 4);
  int*   rowo = (int*)  alloc((size_t)(N + 1) * 4);
  int*   cur  = (int*)  alloc((size_t)N * 4);
  int*   loco = (int*)  alloc((size_t)N * 4);
  int*   bsc  = (int*)  alloc(1024 * 4);
  int*   ssrc = (int*)  alloc((size_t)E * 4);
  int*   sdst = (int*)  alloc((size_t)E * 4);

  ParamPtrs pp; ParamOfs po;
  int hoff[32]; int total = 0;
  for (int s = 0; s < NPAR; ++s){
    int idx = (s < 30) ? (s + 1) : 0;
    pp.p[s] = d_in[idx];
    po.off[s] = total;
    hoff[idx] = total;
    total += in_sizes[idx];
  }
  po.off[NPAR] = total;
  float* pf = (float*)alloc((size_t)total * 4);

  hfr*   P    = (hfr*)  alloc((size_t)N * 64 * 2);
  hfr*   Qb   = (hfr*)  alloc((size_t)N * 64 * 2);
  float* agg  = (float*)alloc((size_t)N * 64 * 4);
  hfr*   xcat = (hfr*)  alloc((size_t)N * 192 * 2);
  hfr* u_l = (hfr*)P;                 // [N,256] f16 over P+Q+agg
  hfr* u1  = xcat;                    // [N,64]  f16
  hfr* u2  = xcat + (size_t)N * 64;   // [N,32]  f16
  (void)ws_size; (void)n_in; (void)out_size;

  dim3 B(256);
  detect_kernel<<<1, B, 0, stream>>>((const bfr*)d_in[0], 256, flag);
  acvt_batch_kernel<<<cdiv(total, 256), B, 0, stream>>>(pp, po, pf, total, flag);

  hipMemsetAsync(stA, 0, 1472 * 4, stream);
  hipMemsetAsync(deg, 0, (size_t)N * 4, stream);
  deg_kernel<<<cdiv(E, 256), B, 0, stream>>>(dst, deg, E);
  const int NBn = cdiv(N, 256);
  scan1_kernel<<<NBn, B, 0, stream>>>(deg, loco, bsc, N);
  scan2_kernel<<<1, B, 0, stream>>>(bsc, NBn);
  scan3_kernel<<<NBn, B, 0, stream>>>(loco, bsc, rowo, cur, N, E);
  scatter_kernel<<<cdiv(E, 256), B, 0, stream>>>(src, dst, cur, ssrc, sdst, E);

  const int NB = cdiv(N, 256);
  const int GWA = 1024, GWB = 1024;
  const float Einv = 1.f / (float)E;
  for (int k = 0; k < 3; ++k){
    const float *Wa_k, *ba_k, *ga_k, *bea_k, *Wb_k, *bb_k, *gb_k, *beb_k;
    if (k == 0){
      Wa_k = pf + hoff[1]; ba_k = pf + hoff[2]; ga_k = pf + hoff[3]; bea_k = pf + hoff[4];
      Wb_k = pf + hoff[5]; bb_k = pf + hoff[6]; gb_k = pf + hoff[7]; beb_k = pf + hoff[8];
    } else {
      int kk = k - 1;
      Wa_k = pf + hoff[9]  + (size_t)kk * 128 * 64;
      ba_k = pf + hoff[10] + kk * 64;
      ga_k = pf + hoff[11] + kk * 64;
      bea_k= pf + hoff[12] + kk * 64;
      Wb_k = pf + hoff[13] + (size_t)kk * 64 * 64;
      bb_k = pf + hoff[14] + kk * 64;
      gb_k = pf + hoff[15] + kk * 64;
      beb_k= pf + hoff[16] + kk * 64;
    }
    float* st1 = stA + k * 256;
    float* st2 = st1 + 128;
    if (k == 0)
      gemmPQ_kernel<true><<<dim3(NB, 2), B, 0, stream>>>(pf + hoff[0], 6, Wa_k, 6, ba_k, P, Qb, N);
    else
      gemmPQ_kernel<false><<<dim3(NB, 2), B, 0, stream>>>(xcat + (size_t)(k - 1) * 64, 192, Wa_k, 64, ba_k, P, Qb, N);
    passA_kernel<<<GWA, B, 0, stream>>>(P, Qb, ssrc, sdst, st1, E);
    passBC_kernel<<<GWB, B, 0, stream>>>(P, Qb, ssrc, rowo, st1, Einv, ga_k, bea_k, Wb_k, bb_k,
                                         agg, st2, N);
    fixup_kernel<<<cdiv(N * 64, 256), B, 0, stream>>>(agg, deg, st2, Einv, gb_k, beb_k,
                                                      xcat + (size_t)k * 64, 192, N);
  }

  // node MLP (folds inlined into consuming GEMMs / head)
  gemm_kernel<64, false><<<dim3(NB, 4), B, 0, stream>>>(xcat, 192, pf + hoff[17], 256, pf + hoff[18],
                                                        nullptr, 0.f, nullptr, nullptr,
                                                        u_l, 256, N, 192, 1);
  statsN_kernel<256><<<512, B, 0, stream>>>(u_l, stN1, N);
  gemm_kernel<64, true><<<dim3(NB, 1), B, 0, stream>>>(u_l, 256, pf + hoff[21], 64, pf + hoff[22],
                                                       stN1, 1.f / (float)N, pf + hoff[19], pf + hoff[20],
                                                       u1, 64, N, 256, 1);
  statsN_kernel<64><<<512, B, 0, stream>>>(u1, stN2, N);
  gemm_kernel<32, true><<<dim3(NB, 1), B, 0, stream>>>(u1, 64, pf + hoff[25], 32, pf + hoff[26],
                                                       stN2, 1.f / (float)N, pf + hoff[23], pf + hoff[24],
                                                       u2, 32, N, 64, 1);
  statsN_kernel<32><<<512, B, 0, stream>>>(u2, stN3, N);
  head_kernel<<<cdiv(N, 256), B, 0, stream>>>(u2, stN3, 1.f / (float)N, pf + hoff[27], pf + hoff[28],
                                              pf + hoff[29], pf + hoff[30], d_out, N, flag);
}